// Round 2
// baseline (8313.870 us; speedup 1.0000x reference)
//
#include <hip/hip_runtime.h>
#include <cstdint>
#include <cstddef>

// Problem constants
#define BDIM 2
#define CDIM 512
#define HDIM 128
#define WDIM 128
#define NDIM (HDIM * WDIM)        // 16384
#define LNUM 6
#define NHEADS 8
#define HEAD_DIM 64
#define NPTS 4
#define BN_TOT (BDIM * NDIM)      // 32768

// ---------------------------------------------------------------------------
// 1) mask[b,n] = all_c (lidar[b,c,n] != 0)
// ---------------------------------------------------------------------------
__global__ void mask_kernel(const float* __restrict__ lidar, int* __restrict__ mask)
{
    int idx = blockIdx.x * blockDim.x + threadIdx.x;      // b*N + n
    if (idx >= BN_TOT) return;
    int b = idx / NDIM;
    int n = idx - b * NDIM;
    const float* p = lidar + (size_t)b * CDIM * NDIM + n;
    int ok = 1;
#pragma unroll 8
    for (int c = 0; c < CDIM; ++c)
        ok &= (p[(size_t)c * NDIM] != 0.0f);
    mask[idx] = ok;
}

// ---------------------------------------------------------------------------
// 2) stable partition: order[pos] = n  (valid rows first, original order kept)
// ---------------------------------------------------------------------------
__global__ void order_kernel(const int* __restrict__ mask, int* __restrict__ order,
                             int* __restrict__ nvalid)
{
    int b = blockIdx.x;
    const int* m = mask + b * NDIM;
    int* ord = order + b * NDIM;
    __shared__ int part[256];
    __shared__ int totalValid;
    int t = threadIdx.x;
    const int CHUNK = NDIM / 256;   // 64
    int base = t * CHUNK;
    int cnt = 0;
    for (int i = 0; i < CHUNK; ++i) cnt += m[base + i];
    part[t] = cnt;
    __syncthreads();
    for (int s = 1; s < 256; s <<= 1) {
        int v = (t >= s) ? part[t - s] : 0;
        __syncthreads();
        part[t] += v;
        __syncthreads();
    }
    if (t == 255) { totalValid = part[255]; nvalid[b] = part[255]; }
    __syncthreads();
    int validBefore = (t == 0) ? 0 : part[t - 1];
    int nv = totalValid;
    for (int i = 0; i < CHUNK; ++i) {
        int n = base + i;
        if (m[n]) { ord[validBefore] = n; validBefore++; }
        else      { int invBefore = n - validBefore; ord[nv + invBefore] = n; }
    }
}

// ---------------------------------------------------------------------------
// 3) ref[b,j,0..1] = (x/W, y/H) of order[j], masked by validity
// ---------------------------------------------------------------------------
__global__ void ref_kernel(const int* __restrict__ order, const int* __restrict__ nvalid,
                           float* __restrict__ ref)
{
    int idx = blockIdx.x * blockDim.x + threadIdx.x;   // b*N + j
    if (idx >= BN_TOT) return;
    int b = idx / NDIM;
    int j = idx - b * NDIM;
    int n = order[idx];
    float flag = (j < nvalid[b]) ? 1.0f : 0.0f;
    int hh = n / WDIM;
    int ww = n - hh * WDIM;
    ref[(size_t)idx * 2 + 0] = ((float)ww / (float)WDIM) * flag;
    ref[(size_t)idx * 2 + 1] = ((float)hh / (float)HDIM) * flag;
}

// ---------------------------------------------------------------------------
// 4) q[b,j,c] = lidar[b,c,order[j]] * valid     (tiled gather+transpose)
// ---------------------------------------------------------------------------
__global__ void pack_q_kernel(const float* __restrict__ lidar, const int* __restrict__ order,
                              const int* __restrict__ nvalid, float* __restrict__ q)
{
    __shared__ float tile[32][33];
    __shared__ int ord_s[32];
    int b  = blockIdx.z;
    int j0 = blockIdx.x * 32;
    int c0 = blockIdx.y * 32;
    int tx = threadIdx.x, ty = threadIdx.y;
    if (ty == 0) ord_s[tx] = order[b * NDIM + j0 + tx];
    __syncthreads();
    const float* src = lidar + (size_t)b * CDIM * NDIM;
#pragma unroll
    for (int k = 0; k < 4; ++k) {
        int cl = ty * 4 + k;
        tile[cl][tx] = src[(size_t)(c0 + cl) * NDIM + ord_s[tx]];
    }
    __syncthreads();
    int nv = nvalid[b];
#pragma unroll
    for (int k = 0; k < 4; ++k) {
        int jl = ty * 4 + k;
        int j = j0 + jl;
        float f = (j < nv) ? 1.0f : 0.0f;
        q[((size_t)b * NDIM + j) * CDIM + c0 + tx] = tile[tx][jl] * f;
    }
}

// ---------------------------------------------------------------------------
// 5) final scatter: out[b,c,order[j]] = q[b,j,c] * valid
// ---------------------------------------------------------------------------
__global__ void scatter_kernel(const float* __restrict__ q, const int* __restrict__ order,
                               const int* __restrict__ nvalid, float* __restrict__ out)
{
    __shared__ float tile[32][33];
    __shared__ int ord_s[32];
    int b  = blockIdx.z;
    int j0 = blockIdx.x * 32;
    int c0 = blockIdx.y * 32;
    int tx = threadIdx.x, ty = threadIdx.y;
    if (ty == 0) ord_s[tx] = order[b * NDIM + j0 + tx];
    __syncthreads();
    int nv = nvalid[b];
#pragma unroll
    for (int k = 0; k < 4; ++k) {
        int jl = ty * 4 + k;
        int j = j0 + jl;
        float f = (j < nv) ? 1.0f : 0.0f;
        tile[jl][tx] = q[((size_t)b * NDIM + j) * CDIM + c0 + tx] * f;
    }
    __syncthreads();
    float* dst = out + (size_t)b * CDIM * NDIM;
#pragma unroll
    for (int k = 0; k < 4; ++k) {
        int cl = ty * 4 + k;
        dst[(size_t)(c0 + cl) * NDIM + ord_s[tx]] = tile[tx][cl];
    }
}

// ---------------------------------------------------------------------------
// 6) PE hidden: h = relu(BN(ref @ pe_W1))
// ---------------------------------------------------------------------------
__global__ void pe_hidden_kernel(const float* __restrict__ ref, const float* __restrict__ W1,
                                 const float* __restrict__ g, const float* __restrict__ bb,
                                 const float* __restrict__ m, const float* __restrict__ v,
                                 float* __restrict__ out)
{
    int row = blockIdx.x;                  // 0 .. BN_TOT-1
    float r0 = ref[(size_t)row * 2 + 0];
    float r1 = ref[(size_t)row * 2 + 1];
    for (int c = threadIdx.x; c < CDIM; c += blockDim.x) {
        float pe = r0 * W1[c] + r1 * W1[CDIM + c];
        pe = (pe - m[c]) * rsqrtf(v[c] + 1e-5f) * g[c] + bb[c];
        out[(size_t)row * CDIM + c] = fmaxf(pe, 0.0f);
    }
}

// ---------------------------------------------------------------------------
// 7) elementwise add: o = a + b (float4)
// ---------------------------------------------------------------------------
__global__ void add_kernel(const float* __restrict__ a, const float* __restrict__ b,
                           float* __restrict__ o, size_t n4)
{
    size_t i = (size_t)blockIdx.x * blockDim.x + threadIdx.x;
    if (i >= n4) return;
    float4 av = ((const float4*)a)[i];
    float4 bv = ((const float4*)b)[i];
    float4 r;
    r.x = av.x + bv.x; r.y = av.y + bv.y; r.z = av.z + bv.z; r.w = av.w + bv.w;
    ((float4*)o)[i] = r;
}

// ---------------------------------------------------------------------------
// 8) generic SGEMM: C = A(MxK) @ B(KxN) [+bias] [+resid] [relu]
//    128x128 block tile, BK=16, 256 threads, 8x8 per thread
// ---------------------------------------------------------------------------
#define TBM 128
#define TBN 128
#define TBK 16

__global__ __launch_bounds__(256) void sgemm_kernel(
    const float* __restrict__ A, const float* __restrict__ Bw,
    const float* __restrict__ bias, const float* __restrict__ resid,
    float* __restrict__ Cout, int M, int Ncols, int K, int doRelu)
{
    __shared__ float As[TBK][TBM + 4];
    __shared__ float Bs[TBK][TBN + 4];
    int tid = threadIdx.x;
    int bm = blockIdx.y * TBM;
    int bn = blockIdx.x * TBN;
    int ty = tid >> 4, tx = tid & 15;

    float acc[8][8];
#pragma unroll
    for (int i = 0; i < 8; ++i)
#pragma unroll
        for (int j = 0; j < 8; ++j) acc[i][j] = 0.0f;

    for (int k0 = 0; k0 < K; k0 += TBK) {
#pragma unroll
        for (int it = 0; it < 2; ++it) {
            int lin = tid + it * 256;
            int arow = lin >> 2;
            int kc = (lin & 3) << 2;
            float4 av = *(const float4*)(A + (size_t)(bm + arow) * K + k0 + kc);
            As[kc + 0][arow] = av.x;
            As[kc + 1][arow] = av.y;
            As[kc + 2][arow] = av.z;
            As[kc + 3][arow] = av.w;
            int krow = lin >> 5;
            int nc = (lin & 31) << 2;
            float4 bv4 = make_float4(0.f, 0.f, 0.f, 0.f);
            if (bn + nc < Ncols)
                bv4 = *(const float4*)(Bw + (size_t)(k0 + krow) * Ncols + bn + nc);
            *(float4*)&Bs[krow][nc] = bv4;
        }
        __syncthreads();
#pragma unroll
        for (int kk = 0; kk < TBK; ++kk) {
            float a[8], bb[8];
            *(float4*)&a[0]  = *(const float4*)&As[kk][ty * 8];
            *(float4*)&a[4]  = *(const float4*)&As[kk][ty * 8 + 4];
            *(float4*)&bb[0] = *(const float4*)&Bs[kk][tx * 8];
            *(float4*)&bb[4] = *(const float4*)&Bs[kk][tx * 8 + 4];
#pragma unroll
            for (int i = 0; i < 8; ++i)
#pragma unroll
                for (int j = 0; j < 8; ++j)
                    acc[i][j] = fmaf(a[i], bb[j], acc[i][j]);
        }
        __syncthreads();
    }

#pragma unroll
    for (int i = 0; i < 8; ++i) {
        int m = bm + ty * 8 + i;
#pragma unroll
        for (int j4 = 0; j4 < 2; ++j4) {
            int n = bn + tx * 8 + j4 * 4;
            if (n < Ncols) {
                float4 r;
                r.x = acc[i][j4 * 4 + 0];
                r.y = acc[i][j4 * 4 + 1];
                r.z = acc[i][j4 * 4 + 2];
                r.w = acc[i][j4 * 4 + 3];
                if (bias) {
                    r.x += bias[n]; r.y += bias[n + 1]; r.z += bias[n + 2]; r.w += bias[n + 3];
                }
                if (resid) {
                    float4 rv = *(const float4*)(resid + (size_t)m * Ncols + n);
                    r.x += rv.x; r.y += rv.y; r.z += rv.z; r.w += rv.w;
                }
                if (doRelu) {
                    r.x = fmaxf(r.x, 0.f); r.y = fmaxf(r.y, 0.f);
                    r.z = fmaxf(r.z, 0.f); r.w = fmaxf(r.w, 0.f);
                }
                *(float4*)(Cout + (size_t)m * Ncols + n) = r;
            }
        }
    }
}

// ---------------------------------------------------------------------------
// 9) SGEMM with A in transposed (B,C,N) layout (bev): row m=b*N+n, col k=c
//    A[m,k] = bev[b*C*N + k*N + n].  Full tiles only (M%128==0, N=512, K=512).
// ---------------------------------------------------------------------------
__global__ __launch_bounds__(256) void sgemm_at_kernel(
    const float* __restrict__ A, const float* __restrict__ Bw,
    const float* __restrict__ bias, float* __restrict__ Cout,
    int Ncols, int K)
{
    __shared__ float As[TBK][TBM + 4];
    __shared__ float Bs[TBK][TBN + 4];
    int tid = threadIdx.x;
    int bm = blockIdx.y * TBM;
    int bn = blockIdx.x * TBN;
    int b  = bm / NDIM;
    int n0 = bm - b * NDIM;
    const float* Ab = A + (size_t)b * CDIM * NDIM + n0;
    int ty = tid >> 4, tx = tid & 15;

    float acc[8][8];
#pragma unroll
    for (int i = 0; i < 8; ++i)
#pragma unroll
        for (int j = 0; j < 8; ++j) acc[i][j] = 0.0f;

    for (int k0 = 0; k0 < K; k0 += TBK) {
#pragma unroll
        for (int it = 0; it < 2; ++it) {
            int lin = tid + it * 256;
            int krow = lin >> 5;           // 0..15
            int mc = (lin & 31) << 2;      // 0..124
            float4 av = *(const float4*)(Ab + (size_t)(k0 + krow) * NDIM + mc);
            *(float4*)&As[krow][mc] = av;
            float4 bv4 = *(const float4*)(Bw + (size_t)(k0 + krow) * Ncols + bn + mc);
            *(float4*)&Bs[krow][mc] = bv4;
        }
        __syncthreads();
#pragma unroll
        for (int kk = 0; kk < TBK; ++kk) {
            float a[8], bb[8];
            *(float4*)&a[0]  = *(const float4*)&As[kk][ty * 8];
            *(float4*)&a[4]  = *(const float4*)&As[kk][ty * 8 + 4];
            *(float4*)&bb[0] = *(const float4*)&Bs[kk][tx * 8];
            *(float4*)&bb[4] = *(const float4*)&Bs[kk][tx * 8 + 4];
#pragma unroll
            for (int i = 0; i < 8; ++i)
#pragma unroll
                for (int j = 0; j < 8; ++j)
                    acc[i][j] = fmaf(a[i], bb[j], acc[i][j]);
        }
        __syncthreads();
    }

#pragma unroll
    for (int i = 0; i < 8; ++i) {
        int m = bm + ty * 8 + i;
#pragma unroll
        for (int j4 = 0; j4 < 2; ++j4) {
            int n = bn + tx * 8 + j4 * 4;
            float4 r;
            r.x = acc[i][j4 * 4 + 0] + bias[n];
            r.y = acc[i][j4 * 4 + 1] + bias[n + 1];
            r.z = acc[i][j4 * 4 + 2] + bias[n + 2];
            r.w = acc[i][j4 * 4 + 3] + bias[n + 3];
            *(float4*)(Cout + (size_t)m * Ncols + n) = r;
        }
    }
}

// ---------------------------------------------------------------------------
// 10) deformable sampling: one wave per (b, j, h); lane = head-dim element
// ---------------------------------------------------------------------------
__global__ __launch_bounds__(256) void sample_kernel(
    const float* __restrict__ ref, const float* __restrict__ off,
    const float* __restrict__ aw, const float* __restrict__ v,
    float* __restrict__ out)
{
    int gw = blockIdx.x * 4 + (threadIdx.x >> 6);   // ((b*N + j)*HEADS + h)
    int lane = threadIdx.x & 63;
    int h = gw & (NHEADS - 1);
    int bj = gw >> 3;                               // b*N + j
    int b = bj / NDIM;

    float rx = ref[(size_t)bj * 2 + 0];
    float ry = ref[(size_t)bj * 2 + 1];
    const float* offp = off + (size_t)bj * 64 + h * 8;
    const float* awp  = aw + (size_t)bj * 32 + h * 4;
    float l0 = awp[0], l1 = awp[1], l2 = awp[2], l3 = awp[3];
    float mx = fmaxf(fmaxf(l0, l1), fmaxf(l2, l3));
    float e[4];
    e[0] = expf(l0 - mx); e[1] = expf(l1 - mx); e[2] = expf(l2 - mx); e[3] = expf(l3 - mx);
    float esum = e[0] + e[1] + e[2] + e[3];

    const float* vb = v + (size_t)b * NDIM * CDIM + h * HEAD_DIM + lane;
    float acc = 0.0f;
#pragma unroll
    for (int p = 0; p < NPTS; ++p) {
        float ox = offp[p * 2 + 0];
        float oy = offp[p * 2 + 1];
        float locx = rx + ox * (1.0f / WDIM);
        float locy = ry + oy * (1.0f / HDIM);
        float X = locx * (float)WDIM - 0.5f;
        float Y = locy * (float)HDIM - 0.5f;
        float x0f = floorf(X), y0f = floorf(Y);
        float wx = X - x0f, wy = Y - y0f;
        int x0 = (int)x0f, y0 = (int)y0f;
        float s = 0.0f;
        if (x0 >= 0 && x0 < WDIM && y0 >= 0 && y0 < HDIM)
            s += (1.0f - wx) * (1.0f - wy) * vb[(size_t)(y0 * WDIM + x0) * CDIM];
        if (x0 + 1 >= 0 && x0 + 1 < WDIM && y0 >= 0 && y0 < HDIM)
            s += wx * (1.0f - wy) * vb[(size_t)(y0 * WDIM + x0 + 1) * CDIM];
        if (x0 >= 0 && x0 < WDIM && y0 + 1 >= 0 && y0 + 1 < HDIM)
            s += (1.0f - wx) * wy * vb[(size_t)((y0 + 1) * WDIM + x0) * CDIM];
        if (x0 + 1 >= 0 && x0 + 1 < WDIM && y0 + 1 >= 0 && y0 + 1 < HDIM)
            s += wx * wy * vb[(size_t)((y0 + 1) * WDIM + x0 + 1) * CDIM];
        acc += e[p] * s;
    }
    out[(size_t)bj * CDIM + h * HEAD_DIM + lane] = acc / esum;
}

// ---------------------------------------------------------------------------
// 11) LayerNorm over C=512; one wave per row, 4 rows per 256-thread block
// ---------------------------------------------------------------------------
__global__ __launch_bounds__(256) void ln_kernel(
    const float* __restrict__ in, const float* __restrict__ g,
    const float* __restrict__ bta, float* __restrict__ out)
{
    int row = blockIdx.x * 4 + (threadIdx.x >> 6);
    int lane = threadIdx.x & 63;
    const float* p = in + (size_t)row * CDIM;
    float4 u = *(const float4*)(p + lane * 4);
    float4 w = *(const float4*)(p + 256 + lane * 4);
    float s = u.x + u.y + u.z + u.w + w.x + w.y + w.z + w.w;
#pragma unroll
    for (int o = 32; o > 0; o >>= 1) s += __shfl_xor(s, o, 64);
    float mu = s * (1.0f / 512.0f);
    float dx;
    float sq = 0.0f;
    dx = u.x - mu; sq += dx * dx;
    dx = u.y - mu; sq += dx * dx;
    dx = u.z - mu; sq += dx * dx;
    dx = u.w - mu; sq += dx * dx;
    dx = w.x - mu; sq += dx * dx;
    dx = w.y - mu; sq += dx * dx;
    dx = w.z - mu; sq += dx * dx;
    dx = w.w - mu; sq += dx * dx;
#pragma unroll
    for (int o = 32; o > 0; o >>= 1) sq += __shfl_xor(sq, o, 64);
    float inv = rsqrtf(sq * (1.0f / 512.0f) + 1e-5f);

    int c0 = lane * 4;
    float4 g0 = *(const float4*)(g + c0);
    float4 b0 = *(const float4*)(bta + c0);
    float4 g1 = *(const float4*)(g + 256 + c0);
    float4 b1 = *(const float4*)(bta + 256 + c0);
    float4 r0, r1;
    r0.x = (u.x - mu) * inv * g0.x + b0.x;
    r0.y = (u.y - mu) * inv * g0.y + b0.y;
    r0.z = (u.z - mu) * inv * g0.z + b0.z;
    r0.w = (u.w - mu) * inv * g0.w + b0.w;
    r1.x = (w.x - mu) * inv * g1.x + b1.x;
    r1.y = (w.y - mu) * inv * g1.y + b1.y;
    r1.z = (w.z - mu) * inv * g1.z + b1.z;
    r1.w = (w.w - mu) * inv * g1.w + b1.w;
    float* q = out + (size_t)row * CDIM;
    *(float4*)(q + c0) = r0;
    *(float4*)(q + 256 + c0) = r1;
}

// ---------------------------------------------------------------------------
// launcher
// ---------------------------------------------------------------------------
extern "C" void kernel_launch(void* const* d_in, const int* in_sizes, int n_in,
                              void* d_out, int out_size, void* d_ws, size_t ws_size,
                              hipStream_t stream)
{
    const float* bev   = (const float*)d_in[0];
    const float* lidar = (const float*)d_in[1];
    const float* Wv    = (const float*)d_in[2];
    const float* bv    = (const float*)d_in[3];
    const float* Woff  = (const float*)d_in[4];
    const float* boff  = (const float*)d_in[5];
    const float* Waw   = (const float*)d_in[6];
    const float* baw   = (const float*)d_in[7];
    const float* Wout  = (const float*)d_in[8];
    const float* bout  = (const float*)d_in[9];
    const float* ln1g  = (const float*)d_in[10];
    const float* ln1b  = (const float*)d_in[11];
    const float* W1    = (const float*)d_in[12];
    const float* W2    = (const float*)d_in[13];
    const float* ln2g  = (const float*)d_in[14];
    const float* ln2b  = (const float*)d_in[15];
    const float* peW1  = (const float*)d_in[16];
    const float* peg   = (const float*)d_in[17];
    const float* peb   = (const float*)d_in[18];
    const float* pem   = (const float*)d_in[19];
    const float* pev   = (const float*)d_in[20];
    const float* peW2  = (const float*)d_in[21];

    // Workspace layout (lean: ~214 MB). qpos lives in d_out until the final
    // scatter overwrites it (d_out is exactly BN_TOT*CDIM floats).
    float* ws = (float*)d_ws;
    const size_t NC = (size_t)BN_TOT * CDIM;    // 16,777,216 floats
    float* q     = ws;                          // NC
    float* xbuf  = ws + 1 * NC;                 // NC: pe-hidden / x / sampled / ffn-hidden
    float* vbuf  = ws + 2 * NC;                 // NC: v / post-attn / post-ffn
    float* offb  = ws + 3 * NC;                 // (BN, 64)
    float* awb   = offb + (size_t)BN_TOT * 64;  // (BN, 32)
    float* refb  = awb + (size_t)BN_TOT * 32;   // (BN, 2)
    int* mask    = (int*)(refb + (size_t)BN_TOT * 2);
    int* order   = mask + BN_TOT;
    int* nvalid  = order + BN_TOT;
    float* qpos  = (float*)d_out;               // NC (dead before final scatter)

    // voxelize
    mask_kernel<<<BN_TOT / 256, 256, 0, stream>>>(lidar, mask);
    order_kernel<<<BDIM, 256, 0, stream>>>(mask, order, nvalid);
    ref_kernel<<<BN_TOT / 256, 256, 0, stream>>>(order, nvalid, refb);
    {
        dim3 g(NDIM / 32, CDIM / 32, BDIM), blk(32, 8);
        pack_q_kernel<<<g, blk, 0, stream>>>(lidar, order, nvalid, q);
    }

    // positional embedding
    pe_hidden_kernel<<<BN_TOT, 128, 0, stream>>>(refb, peW1, peg, peb, pem, pev, xbuf);
    dim3 gg(CDIM / TBN, BN_TOT / TBM);
    sgemm_kernel<<<gg, 256, 0, stream>>>(xbuf, peW2, nullptr, nullptr, qpos,
                                         BN_TOT, CDIM, CDIM, 0);

    const size_t n4 = NC / 4;
    dim3 g64(1, BN_TOT / TBM);

    for (int i = 0; i < LNUM; ++i) {
        // x = q + q_pos
        add_kernel<<<(unsigned)((n4 + 255) / 256), 256, 0, stream>>>(q, qpos, xbuf, n4);
        // v = bev^T @ Wv + bv   (A read directly from (B,C,N) layout)
        sgemm_at_kernel<<<gg, 256, 0, stream>>>(bev, Wv + (size_t)i * CDIM * CDIM,
                                                bv + i * CDIM, vbuf, CDIM, CDIM);
        // off, aw
        sgemm_kernel<<<g64, 256, 0, stream>>>(xbuf, Woff + (size_t)i * CDIM * 64,
                                              boff + i * 64, nullptr, offb,
                                              BN_TOT, 64, CDIM, 0);
        sgemm_kernel<<<g64, 256, 0, stream>>>(xbuf, Waw + (size_t)i * CDIM * 32,
                                              baw + i * 32, nullptr, awb,
                                              BN_TOT, 32, CDIM, 0);
        // deformable sampling -> xbuf (x is dead now)
        sample_kernel<<<BN_TOT * NHEADS / 4, 256, 0, stream>>>(refb, offb, awb, vbuf, xbuf);
        // q' = sampled @ Wout + bout + q   -> vbuf
        sgemm_kernel<<<gg, 256, 0, stream>>>(xbuf, Wout + (size_t)i * CDIM * CDIM,
                                             bout + i * CDIM, q, vbuf,
                                             BN_TOT, CDIM, CDIM, 0);
        // q = LN1(vbuf)
        ln_kernel<<<BN_TOT / 4, 256, 0, stream>>>(vbuf, ln1g + i * CDIM, ln1b + i * CDIM, q);
        // h = relu(q @ W1) -> xbuf
        sgemm_kernel<<<gg, 256, 0, stream>>>(q, W1 + (size_t)i * CDIM * CDIM,
                                             nullptr, nullptr, xbuf,
                                             BN_TOT, CDIM, CDIM, 1);
        // q2 = h @ W2 + q -> vbuf
        sgemm_kernel<<<gg, 256, 0, stream>>>(xbuf, W2 + (size_t)i * CDIM * CDIM,
                                             nullptr, q, vbuf,
                                             BN_TOT, CDIM, CDIM, 0);
        // q = LN2(vbuf)
        ln_kernel<<<BN_TOT / 4, 256, 0, stream>>>(vbuf, ln2g + i * CDIM, ln2b + i * CDIM, q);
    }

    // scatter back to dense (B, C, H, W)
    {
        dim3 g(NDIM / 32, CDIM / 32, BDIM), blk(32, 8);
        scatter_kernel<<<g, blk, 0, stream>>>(q, order, nvalid, (float*)d_out);
    }
}

// Round 3
// 3502.851 us; speedup vs baseline: 2.3735x; 2.3735x over previous
//
#include <hip/hip_runtime.h>
#include <cstdint>
#include <cstddef>

// Problem constants
#define BDIM 2
#define CDIM 512
#define HDIM 128
#define WDIM 128
#define NDIM (HDIM * WDIM)        // 16384
#define LNUM 6
#define NHEADS 8
#define HEAD_DIM 64
#define NPTS 4
#define BN_TOT (BDIM * NDIM)      // 32768

typedef unsigned short u16;
typedef __attribute__((ext_vector_type(8))) short bf16x8;   // 8 bf16 = 4 VGPRs
typedef __attribute__((ext_vector_type(4))) float f32x4;    // MFMA accum

__device__ __forceinline__ u16 f2bf(float x) {              // RNE fp32->bf16
    unsigned u = __float_as_uint(x);
    u += 0x7fffu + ((u >> 16) & 1u);
    return (u16)(u >> 16);
}
__device__ __forceinline__ float bf2f(u16 h) {
    return __uint_as_float(((unsigned)h) << 16);
}

__device__ __forceinline__ void load_lds16(const void* g, void* l) {
    // async global->LDS, 16B/lane; LDS dest = wave-uniform base + lane*16
    __builtin_amdgcn_global_load_lds(
        (const __attribute__((address_space(1))) void*)g,
        (__attribute__((address_space(3))) void*)l, 16, 0, 0);
}

// ---------------------------------------------------------------------------
// voxelization: mask / order / ref / pack_q  (unchanged fp32)
// ---------------------------------------------------------------------------
__global__ void mask_kernel(const float* __restrict__ lidar, int* __restrict__ mask)
{
    int idx = blockIdx.x * blockDim.x + threadIdx.x;
    if (idx >= BN_TOT) return;
    int b = idx / NDIM;
    int n = idx - b * NDIM;
    const float* p = lidar + (size_t)b * CDIM * NDIM + n;
    int ok = 1;
#pragma unroll 8
    for (int c = 0; c < CDIM; ++c)
        ok &= (p[(size_t)c * NDIM] != 0.0f);
    mask[idx] = ok;
}

__global__ void order_kernel(const int* __restrict__ mask, int* __restrict__ order,
                             int* __restrict__ nvalid)
{
    int b = blockIdx.x;
    const int* m = mask + b * NDIM;
    int* ord = order + b * NDIM;
    __shared__ int part[256];
    __shared__ int totalValid;
    int t = threadIdx.x;
    const int CHUNK = NDIM / 256;
    int base = t * CHUNK;
    int cnt = 0;
    for (int i = 0; i < CHUNK; ++i) cnt += m[base + i];
    part[t] = cnt;
    __syncthreads();
    for (int s = 1; s < 256; s <<= 1) {
        int v = (t >= s) ? part[t - s] : 0;
        __syncthreads();
        part[t] += v;
        __syncthreads();
    }
    if (t == 255) { totalValid = part[255]; nvalid[b] = part[255]; }
    __syncthreads();
    int validBefore = (t == 0) ? 0 : part[t - 1];
    int nv = totalValid;
    for (int i = 0; i < CHUNK; ++i) {
        int n = base + i;
        if (m[n]) { ord[validBefore] = n; validBefore++; }
        else      { int invBefore = n - validBefore; ord[nv + invBefore] = n; }
    }
}

__global__ void ref_kernel(const int* __restrict__ order, const int* __restrict__ nvalid,
                           float* __restrict__ ref)
{
    int idx = blockIdx.x * blockDim.x + threadIdx.x;
    if (idx >= BN_TOT) return;
    int b = idx / NDIM;
    int j = idx - b * NDIM;
    int n = order[idx];
    float flag = (j < nvalid[b]) ? 1.0f : 0.0f;
    int hh = n / WDIM;
    int ww = n - hh * WDIM;
    ref[(size_t)idx * 2 + 0] = ((float)ww / (float)WDIM) * flag;
    ref[(size_t)idx * 2 + 1] = ((float)hh / (float)HDIM) * flag;
}

__global__ void pack_q_kernel(const float* __restrict__ lidar, const int* __restrict__ order,
                              const int* __restrict__ nvalid, float* __restrict__ q)
{
    __shared__ float tile[32][33];
    __shared__ int ord_s[32];
    int b  = blockIdx.z;
    int j0 = blockIdx.x * 32;
    int c0 = blockIdx.y * 32;
    int tx = threadIdx.x, ty = threadIdx.y;
    if (ty == 0) ord_s[tx] = order[b * NDIM + j0 + tx];
    __syncthreads();
    const float* src = lidar + (size_t)b * CDIM * NDIM;
#pragma unroll
    for (int k = 0; k < 4; ++k) {
        int cl = ty * 4 + k;
        tile[cl][tx] = src[(size_t)(c0 + cl) * NDIM + ord_s[tx]];
    }
    __syncthreads();
    int nv = nvalid[b];
#pragma unroll
    for (int k = 0; k < 4; ++k) {
        int jl = ty * 4 + k;
        int j = j0 + jl;
        float f = (j < nv) ? 1.0f : 0.0f;
        q[((size_t)b * NDIM + j) * CDIM + c0 + tx] = tile[tx][jl] * f;
    }
}

__global__ void scatter_kernel(const float* __restrict__ q, const int* __restrict__ order,
                               const int* __restrict__ nvalid, float* __restrict__ out)
{
    __shared__ float tile[32][33];
    __shared__ int ord_s[32];
    int b  = blockIdx.z;
    int j0 = blockIdx.x * 32;
    int c0 = blockIdx.y * 32;
    int tx = threadIdx.x, ty = threadIdx.y;
    if (ty == 0) ord_s[tx] = order[b * NDIM + j0 + tx];
    __syncthreads();
    int nv = nvalid[b];
#pragma unroll
    for (int k = 0; k < 4; ++k) {
        int jl = ty * 4 + k;
        int j = j0 + jl;
        float f = (j < nv) ? 1.0f : 0.0f;
        tile[jl][tx] = q[((size_t)b * NDIM + j) * CDIM + c0 + tx] * f;
    }
    __syncthreads();
    float* dst = out + (size_t)b * CDIM * NDIM;
#pragma unroll
    for (int k = 0; k < 4; ++k) {
        int cl = ty * 4 + k;
        dst[(size_t)(c0 + cl) * NDIM + ord_s[tx]] = tile[tx][cl];
    }
}

// ---------------------------------------------------------------------------
// weight transpose-convert: src fp32 [K=512][N=512] -> dst bf16 [N][K]
// ---------------------------------------------------------------------------
__global__ void tconv_kernel(const float* __restrict__ src, u16* __restrict__ dst)
{
    __shared__ float t[32][33];
    int k0 = blockIdx.x * 32, n0 = blockIdx.y * 32;
    int tx = threadIdx.x, ty = threadIdx.y;
#pragma unroll
    for (int j = 0; j < 4; ++j) {
        int kl = ty * 4 + j;
        t[kl][tx] = src[(size_t)(k0 + kl) * 512 + n0 + tx];
    }
    __syncthreads();
#pragma unroll
    for (int j = 0; j < 4; ++j) {
        int nl = ty * 4 + j;
        dst[(size_t)(n0 + nl) * 512 + k0 + tx] = f2bf(t[tx][nl]);
    }
}

// Woff [512][64] + Waw [512][32] -> dst bf16 [96][512] (row n = output col)
__global__ void tconv_offaw_kernel(const float* __restrict__ woff,
                                   const float* __restrict__ waw,
                                   u16* __restrict__ dst)
{
    __shared__ float t[32][33];
    int k0 = blockIdx.x * 32, n0 = blockIdx.y * 32;
    int tx = threadIdx.x, ty = threadIdx.y;
#pragma unroll
    for (int j = 0; j < 4; ++j) {
        int kl = ty * 4 + j;
        int n = n0 + tx;
        float v = (n < 64) ? woff[(size_t)(k0 + kl) * 64 + n]
                           : waw[(size_t)(k0 + kl) * 32 + (n - 64)];
        t[kl][tx] = v;
    }
    __syncthreads();
#pragma unroll
    for (int j = 0; j < 4; ++j) {
        int nl = ty * 4 + j;
        dst[(size_t)(n0 + nl) * 512 + k0 + tx] = f2bf(t[tx][nl]);
    }
}

// bev (B,C,N) fp32 -> featT (B,N,C) bf16
__global__ void bev_conv_kernel(const float* __restrict__ bev, u16* __restrict__ dst)
{
    __shared__ float t[32][33];
    int b  = blockIdx.z;
    int n0 = blockIdx.x * 32;
    int c0 = blockIdx.y * 32;
    int tx = threadIdx.x, ty = threadIdx.y;
    const float* src = bev + (size_t)b * CDIM * NDIM;
#pragma unroll
    for (int j = 0; j < 4; ++j) {
        int cl = ty * 4 + j;
        t[cl][tx] = src[(size_t)(c0 + cl) * NDIM + n0 + tx];
    }
    __syncthreads();
#pragma unroll
    for (int j = 0; j < 4; ++j) {
        int nl = ty * 4 + j;
        dst[((size_t)b * NDIM + n0 + nl) * CDIM + c0 + tx] = f2bf(t[tx][nl]);
    }
}

// ---------------------------------------------------------------------------
// PE hidden: h = relu(BN(ref @ pe_W1))  -> bf16
// ---------------------------------------------------------------------------
__global__ void pe_hidden_kernel(const float* __restrict__ ref, const float* __restrict__ W1,
                                 const float* __restrict__ g, const float* __restrict__ bb,
                                 const float* __restrict__ m, const float* __restrict__ v,
                                 u16* __restrict__ out)
{
    int row = blockIdx.x;
    float r0 = ref[(size_t)row * 2 + 0];
    float r1 = ref[(size_t)row * 2 + 1];
    for (int c = threadIdx.x; c < CDIM; c += blockDim.x) {
        float pe = r0 * W1[c] + r1 * W1[CDIM + c];
        pe = (pe - m[c]) * rsqrtf(v[c] + 1e-5f) * g[c] + bb[c];
        out[(size_t)row * CDIM + c] = f2bf(fmaxf(pe, 0.0f));
    }
}

// ---------------------------------------------------------------------------
// x = q(fp32) + qpos(bf16) -> bf16 ; 8 elements/thread
// ---------------------------------------------------------------------------
__global__ void add_bf_kernel(const float* __restrict__ q, const u16* __restrict__ qpos,
                              u16* __restrict__ x)
{
    size_t i = (size_t)blockIdx.x * blockDim.x + threadIdx.x;  // 8-el group
    const float4* qp = (const float4*)q + i * 2;
    float4 a = qp[0], b = qp[1];
    uint4 pv = ((const uint4*)qpos)[i];
    float p0 = bf2f((u16)(pv.x & 0xffff)), p1 = bf2f((u16)(pv.x >> 16));
    float p2 = bf2f((u16)(pv.y & 0xffff)), p3 = bf2f((u16)(pv.y >> 16));
    float p4 = bf2f((u16)(pv.z & 0xffff)), p5 = bf2f((u16)(pv.z >> 16));
    float p6 = bf2f((u16)(pv.w & 0xffff)), p7 = bf2f((u16)(pv.w >> 16));
    uint4 r;
    r.x = (unsigned)f2bf(a.x + p0) | ((unsigned)f2bf(a.y + p1) << 16);
    r.y = (unsigned)f2bf(a.z + p2) | ((unsigned)f2bf(a.w + p3) << 16);
    r.z = (unsigned)f2bf(b.x + p4) | ((unsigned)f2bf(b.y + p5) << 16);
    r.w = (unsigned)f2bf(b.z + p6) | ((unsigned)f2bf(b.w + p7) << 16);
    ((uint4*)x)[i] = r;
}

// ---------------------------------------------------------------------------
// MFMA bf16 GEMM: C[M=32768][512] = A[M][512]bf16 @ Bt[512][512]^T bf16
// Bt is [n][k] row-major (K-contiguous). 128x128 tile, BK=32, 4 waves.
// Epilogue: +bias, +resid(fp32), relu, write fp32 and/or bf16.
// ---------------------------------------------------------------------------
__global__ __launch_bounds__(256) void gemm_bf16(
    const u16* __restrict__ A, const u16* __restrict__ Bt,
    const float* __restrict__ bias, const float* __restrict__ resid,
    float* __restrict__ outF, u16* __restrict__ outB, int relu)
{
    __shared__ u16 As[128 * 32];
    __shared__ u16 Bs[128 * 32];
    int tid = threadIdx.x;
    int wave = tid >> 6, lane = tid & 63;
    int wr = wave >> 1, wc = wave & 1;
    int quad = lane >> 4, l15 = lane & 15;
    int bm = blockIdx.y * 128, bn = blockIdx.x * 128;

    f32x4 acc[4][4];
#pragma unroll
    for (int i = 0; i < 4; ++i)
#pragma unroll
        for (int j = 0; j < 4; ++j) { f32x4 z = {0.f, 0.f, 0.f, 0.f}; acc[i][j] = z; }

    // staging: tile 128x32 bf16 = 8192B = 8 segments of 1024B; wave w does segs w, w+4
    int e0 = wave * 512 + lane * 8;
    int e1 = (wave + 4) * 512 + lane * 8;
    const u16* Ag0 = A + (size_t)(bm + (e0 >> 5)) * 512 + (e0 & 31);
    const u16* Ag1 = A + (size_t)(bm + (e1 >> 5)) * 512 + (e1 & 31);
    const u16* Bg0 = Bt + (size_t)(bn + (e0 >> 5)) * 512 + (e0 & 31);
    const u16* Bg1 = Bt + (size_t)(bn + (e1 >> 5)) * 512 + (e1 & 31);

    for (int k0 = 0; k0 < 512; k0 += 32) {
        load_lds16(Ag0 + k0, &As[wave * 512]);
        load_lds16(Ag1 + k0, &As[(wave + 4) * 512]);
        load_lds16(Bg0 + k0, &Bs[wave * 512]);
        load_lds16(Bg1 + k0, &Bs[(wave + 4) * 512]);
        __syncthreads();
        bf16x8 av[4], bv[4];
#pragma unroll
        for (int mi = 0; mi < 4; ++mi)
            av[mi] = *(const bf16x8*)&As[(wr * 64 + mi * 16 + l15) * 32 + quad * 8];
#pragma unroll
        for (int ni = 0; ni < 4; ++ni)
            bv[ni] = *(const bf16x8*)&Bs[(wc * 64 + ni * 16 + l15) * 32 + quad * 8];
#pragma unroll
        for (int mi = 0; mi < 4; ++mi)
#pragma unroll
            for (int ni = 0; ni < 4; ++ni)
                acc[mi][ni] = __builtin_amdgcn_mfma_f32_16x16x32_bf16(
                    av[mi], bv[ni], acc[mi][ni], 0, 0, 0);
        __syncthreads();
    }

    int rowb = bm + wr * 64;
    int colb = bn + wc * 64;
#pragma unroll
    for (int mi = 0; mi < 4; ++mi) {
#pragma unroll
        for (int ni = 0; ni < 4; ++ni) {
            int col = colb + ni * 16 + l15;
            float bi = bias ? bias[col] : 0.0f;
#pragma unroll
            for (int r = 0; r < 4; ++r) {
                int row = rowb + mi * 16 + quad * 4 + r;
                float val = acc[mi][ni][r] + bi;
                size_t o = (size_t)row * 512 + col;
                if (resid) val += resid[o];
                if (relu) val = fmaxf(val, 0.0f);
                if (outF) outF[o] = val;
                if (outB) outB[o] = f2bf(val);
            }
        }
    }
}

// ---------------------------------------------------------------------------
// fused off+aw GEMM: A[M][512]bf16 @ OffAwT[96][512]bf16 -> offb[M][64]bf16,
// awb[M][32]bf16. Single n-block (BN=128, cols >=96 discarded).
// ---------------------------------------------------------------------------
__global__ __launch_bounds__(256) void gemm_offaw(
    const u16* __restrict__ A, const u16* __restrict__ Bt,
    const float* __restrict__ boff, const float* __restrict__ baw,
    u16* __restrict__ offb, u16* __restrict__ awb)
{
    __shared__ u16 As[128 * 32];
    __shared__ u16 Bs[128 * 32];
    int tid = threadIdx.x;
    int wave = tid >> 6, lane = tid & 63;
    int wr = wave >> 1, wc = wave & 1;
    int quad = lane >> 4, l15 = lane & 15;
    int bm = blockIdx.y * 128;

    f32x4 acc[4][4];
#pragma unroll
    for (int i = 0; i < 4; ++i)
#pragma unroll
        for (int j = 0; j < 4; ++j) { f32x4 z = {0.f, 0.f, 0.f, 0.f}; acc[i][j] = z; }

    int e0 = wave * 512 + lane * 8;
    int e1 = (wave + 4) * 512 + lane * 8;
    int br0 = e0 >> 5; if (br0 > 95) br0 = 95;   // clamp: garbage cols unused
    int br1 = e1 >> 5; if (br1 > 95) br1 = 95;
    const u16* Ag0 = A + (size_t)(bm + (e0 >> 5)) * 512 + (e0 & 31);
    const u16* Ag1 = A + (size_t)(bm + (e1 >> 5)) * 512 + (e1 & 31);
    const u16* Bg0 = Bt + (size_t)br0 * 512 + (e0 & 31);
    const u16* Bg1 = Bt + (size_t)br1 * 512 + (e1 & 31);

    for (int k0 = 0; k0 < 512; k0 += 32) {
        load_lds16(Ag0 + k0, &As[wave * 512]);
        load_lds16(Ag1 + k0, &As[(wave + 4) * 512]);
        load_lds16(Bg0 + k0, &Bs[wave * 512]);
        load_lds16(Bg1 + k0, &Bs[(wave + 4) * 512]);
        __syncthreads();
        bf16x8 av[4], bv[4];
#pragma unroll
        for (int mi = 0; mi < 4; ++mi)
            av[mi] = *(const bf16x8*)&As[(wr * 64 + mi * 16 + l15) * 32 + quad * 8];
#pragma unroll
        for (int ni = 0; ni < 4; ++ni)
            bv[ni] = *(const bf16x8*)&Bs[(wc * 64 + ni * 16 + l15) * 32 + quad * 8];
#pragma unroll
        for (int mi = 0; mi < 4; ++mi)
#pragma unroll
            for (int ni = 0; ni < 4; ++ni)
                acc[mi][ni] = __builtin_amdgcn_mfma_f32_16x16x32_bf16(
                    av[mi], bv[ni], acc[mi][ni], 0, 0, 0);
        __syncthreads();
    }

    int rowb = bm + wr * 64;
#pragma unroll
    for (int mi = 0; mi < 4; ++mi) {
#pragma unroll
        for (int ni = 0; ni < 4; ++ni) {
            int col = wc * 64 + ni * 16 + l15;
            if (col < 96) {
                float bi = (col < 64) ? boff[col] : baw[col - 64];
#pragma unroll
                for (int r = 0; r < 4; ++r) {
                    int row = rowb + mi * 16 + quad * 4 + r;
                    float val = acc[mi][ni][r] + bi;
                    if (col < 64) offb[(size_t)row * 64 + col] = f2bf(val);
                    else          awb[(size_t)row * 32 + (col - 64)] = f2bf(val);
                }
            }
        }
    }
}

// ---------------------------------------------------------------------------
// deformable sampling: one wave per (b, j, h); lane = head-dim element (bf16)
// ---------------------------------------------------------------------------
__global__ __launch_bounds__(256) void sample_kernel(
    const float* __restrict__ ref, const u16* __restrict__ off,
    const u16* __restrict__ aw, const u16* __restrict__ v,
    u16* __restrict__ out)
{
    int gw = blockIdx.x * 4 + (threadIdx.x >> 6);   // ((b*N + j)*HEADS + h)
    int lane = threadIdx.x & 63;
    int h = gw & (NHEADS - 1);
    int bj = gw >> 3;
    int b = bj / NDIM;

    float rx = ref[(size_t)bj * 2 + 0];
    float ry = ref[(size_t)bj * 2 + 1];
    const u16* offp = off + (size_t)bj * 64 + h * 8;
    const u16* awp  = aw + (size_t)bj * 32 + h * 4;
    float l0 = bf2f(awp[0]), l1 = bf2f(awp[1]), l2 = bf2f(awp[2]), l3 = bf2f(awp[3]);
    float mx = fmaxf(fmaxf(l0, l1), fmaxf(l2, l3));
    float e[4];
    e[0] = expf(l0 - mx); e[1] = expf(l1 - mx); e[2] = expf(l2 - mx); e[3] = expf(l3 - mx);
    float esum = e[0] + e[1] + e[2] + e[3];

    const u16* vb = v + (size_t)b * NDIM * CDIM + h * HEAD_DIM + lane;
    float acc = 0.0f;
#pragma unroll
    for (int p = 0; p < NPTS; ++p) {
        float ox = bf2f(offp[p * 2 + 0]);
        float oy = bf2f(offp[p * 2 + 1]);
        float X = (rx + ox * (1.0f / WDIM)) * (float)WDIM - 0.5f;
        float Y = (ry + oy * (1.0f / HDIM)) * (float)HDIM - 0.5f;
        float x0f = floorf(X), y0f = floorf(Y);
        float wx = X - x0f, wy = Y - y0f;
        int x0 = (int)x0f, y0 = (int)y0f;
        float s = 0.0f;
        if (x0 >= 0 && x0 < WDIM && y0 >= 0 && y0 < HDIM)
            s += (1.0f - wx) * (1.0f - wy) * bf2f(vb[(size_t)(y0 * WDIM + x0) * CDIM]);
        if (x0 + 1 >= 0 && x0 + 1 < WDIM && y0 >= 0 && y0 < HDIM)
            s += wx * (1.0f - wy) * bf2f(vb[(size_t)(y0 * WDIM + x0 + 1) * CDIM]);
        if (x0 >= 0 && x0 < WDIM && y0 + 1 >= 0 && y0 + 1 < HDIM)
            s += (1.0f - wx) * wy * bf2f(vb[(size_t)((y0 + 1) * WDIM + x0) * CDIM]);
        if (x0 + 1 >= 0 && x0 + 1 < WDIM && y0 + 1 >= 0 && y0 + 1 < HDIM)
            s += wx * wy * bf2f(vb[(size_t)((y0 + 1) * WDIM + x0 + 1) * CDIM]);
        acc += e[p] * s;
    }
    out[(size_t)bj * CDIM + h * HEAD_DIM + lane] = f2bf(acc / esum);
}

// ---------------------------------------------------------------------------
// LayerNorm over C=512; fp32 out + optional bf16 copy
// ---------------------------------------------------------------------------
__global__ __launch_bounds__(256) void ln_kernel(
    const float* __restrict__ in, const float* __restrict__ g,
    const float* __restrict__ bta, float* __restrict__ out, u16* __restrict__ outbf)
{
    int row = blockIdx.x * 4 + (threadIdx.x >> 6);
    int lane = threadIdx.x & 63;
    const float* p = in + (size_t)row * CDIM;
    float4 u = *(const float4*)(p + lane * 4);
    float4 w = *(const float4*)(p + 256 + lane * 4);
    float s = u.x + u.y + u.z + u.w + w.x + w.y + w.z + w.w;
#pragma unroll
    for (int o = 32; o > 0; o >>= 1) s += __shfl_xor(s, o, 64);
    float mu = s * (1.0f / 512.0f);
    float dx, sq = 0.0f;
    dx = u.x - mu; sq += dx * dx;  dx = u.y - mu; sq += dx * dx;
    dx = u.z - mu; sq += dx * dx;  dx = u.w - mu; sq += dx * dx;
    dx = w.x - mu; sq += dx * dx;  dx = w.y - mu; sq += dx * dx;
    dx = w.z - mu; sq += dx * dx;  dx = w.w - mu; sq += dx * dx;
#pragma unroll
    for (int o = 32; o > 0; o >>= 1) sq += __shfl_xor(sq, o, 64);
    float inv = rsqrtf(sq * (1.0f / 512.0f) + 1e-5f);

    int c0 = lane * 4;
    float4 g0 = *(const float4*)(g + c0);
    float4 b0 = *(const float4*)(bta + c0);
    float4 g1 = *(const float4*)(g + 256 + c0);
    float4 b1 = *(const float4*)(bta + 256 + c0);
    float4 r0, r1;
    r0.x = (u.x - mu) * inv * g0.x + b0.x;
    r0.y = (u.y - mu) * inv * g0.y + b0.y;
    r0.z = (u.z - mu) * inv * g0.z + b0.z;
    r0.w = (u.w - mu) * inv * g0.w + b0.w;
    r1.x = (w.x - mu) * inv * g1.x + b1.x;
    r1.y = (w.y - mu) * inv * g1.y + b1.y;
    r1.z = (w.z - mu) * inv * g1.z + b1.z;
    r1.w = (w.w - mu) * inv * g1.w + b1.w;
    float* qo = out + (size_t)row * CDIM;
    *(float4*)(qo + c0) = r0;
    *(float4*)(qo + 256 + c0) = r1;
    if (outbf) {
        u16* qb = outbf + (size_t)row * CDIM;
        uint2 pk0, pk1;
        pk0.x = (unsigned)f2bf(r0.x) | ((unsigned)f2bf(r0.y) << 16);
        pk0.y = (unsigned)f2bf(r0.z) | ((unsigned)f2bf(r0.w) << 16);
        pk1.x = (unsigned)f2bf(r1.x) | ((unsigned)f2bf(r1.y) << 16);
        pk1.y = (unsigned)f2bf(r1.z) | ((unsigned)f2bf(r1.w) << 16);
        *(uint2*)(qb + c0) = pk0;
        *(uint2*)(qb + 256 + c0) = pk1;
    }
}

// ---------------------------------------------------------------------------
// launcher
// ---------------------------------------------------------------------------
extern "C" void kernel_launch(void* const* d_in, const int* in_sizes, int n_in,
                              void* d_out, int out_size, void* d_ws, size_t ws_size,
                              hipStream_t stream)
{
    const float* bev   = (const float*)d_in[0];
    const float* lidar = (const float*)d_in[1];
    const float* Wv    = (const float*)d_in[2];
    const float* bv    = (const float*)d_in[3];
    const float* Woff  = (const float*)d_in[4];
    const float* boff  = (const float*)d_in[5];
    const float* Waw   = (const float*)d_in[6];
    const float* baw   = (const float*)d_in[7];
    const float* Wout  = (const float*)d_in[8];
    const float* bout  = (const float*)d_in[9];
    const float* ln1g  = (const float*)d_in[10];
    const float* ln1b  = (const float*)d_in[11];
    const float* W1    = (const float*)d_in[12];
    const float* W2    = (const float*)d_in[13];
    const float* ln2g  = (const float*)d_in[14];
    const float* ln2b  = (const float*)d_in[15];
    const float* peW1  = (const float*)d_in[16];
    const float* peg   = (const float*)d_in[17];
    const float* peb   = (const float*)d_in[18];
    const float* pem   = (const float*)d_in[19];
    const float* pev   = (const float*)d_in[20];
    const float* peW2  = (const float*)d_in[21];

    const size_t NC = (size_t)BN_TOT * CDIM;    // 16,777,216

    // workspace (~210 MB, under round-2's proven 214 MB)
    char* base = (char*)d_ws;
    float* q     = (float*)base;                        // NC fp32
    float* tmp   = (float*)(base + NC * 4);             // NC fp32
    u16* actA    = (u16*)(base + NC * 8);               // NC bf16
    u16* actB    = (u16*)(base + NC * 10);              // NC bf16
    u16* wt      = (u16*)(base + NC * 12);              // 4 x 512x512 bf16
    u16* offawt  = wt + 4 * 512 * 512;                  // 96x512 bf16
    u16* offb    = offawt + 96 * 512;                   // BN x 64 bf16
    u16* awb     = offb + (size_t)BN_TOT * 64;          // BN x 32 bf16
    float* refb  = (float*)(awb + (size_t)BN_TOT * 32); // BN x 2 fp32
    int* mask    = (int*)(refb + (size_t)BN_TOT * 2);
    int* order   = mask + BN_TOT;
    int* nvalid  = order + BN_TOT;

    // d_out doubles as scratch until final scatter:
    u16* qpos_bf = (u16*)d_out;                         // NC bf16 (first half)
    u16* featT   = (u16*)d_out + NC;                    // NC bf16 (second half)

    dim3 blk328(32, 8);
    dim3 gemm_grid(4, 256);
    dim3 offaw_grid(1, 256);

    // voxelize
    mask_kernel<<<BN_TOT / 256, 256, 0, stream>>>(lidar, mask);
    order_kernel<<<BDIM, 256, 0, stream>>>(mask, order, nvalid);
    ref_kernel<<<BN_TOT / 256, 256, 0, stream>>>(order, nvalid, refb);
    pack_q_kernel<<<dim3(NDIM / 32, CDIM / 32, BDIM), blk328, 0, stream>>>(lidar, order, nvalid, q);
    bev_conv_kernel<<<dim3(NDIM / 32, CDIM / 32, BDIM), blk328, 0, stream>>>(bev, featT);

    // positional embedding: qpos_bf = relu(BN(ref@peW1)) @ peW2
    pe_hidden_kernel<<<BN_TOT, 128, 0, stream>>>(refb, peW1, peg, peb, pem, pev, actA);
    tconv_kernel<<<dim3(16, 16), blk328, 0, stream>>>(peW2, wt);
    gemm_bf16<<<gemm_grid, 256, 0, stream>>>(actA, wt, nullptr, nullptr,
                                             nullptr, qpos_bf, 0);

    for (int i = 0; i < LNUM; ++i) {
        const size_t WO = (size_t)i * CDIM * CDIM;
        // per-layer weight conversion (transposed bf16)
        tconv_kernel<<<dim3(16, 16), blk328, 0, stream>>>(Wv + WO,   wt + 0 * 262144);
        tconv_kernel<<<dim3(16, 16), blk328, 0, stream>>>(Wout + WO, wt + 1 * 262144);
        tconv_kernel<<<dim3(16, 16), blk328, 0, stream>>>(W1 + WO,   wt + 2 * 262144);
        tconv_kernel<<<dim3(16, 16), blk328, 0, stream>>>(W2 + WO,   wt + 3 * 262144);
        tconv_offaw_kernel<<<dim3(16, 3), blk328, 0, stream>>>(
            Woff + (size_t)i * CDIM * 64, Waw + (size_t)i * CDIM * 32, offawt);

        // x = q + qpos  -> actA (bf16)
        add_bf_kernel<<<(unsigned)(NC / 8 / 256), 256, 0, stream>>>(q, qpos_bf, actA);
        // off/aw = x @ [Woff|Waw] + bias  -> offb/awb (bf16)
        gemm_offaw<<<offaw_grid, 256, 0, stream>>>(actA, offawt,
                                                   boff + i * 64, baw + i * 32, offb, awb);
        // v = featT @ Wv + bv -> actA (x dead)
        gemm_bf16<<<gemm_grid, 256, 0, stream>>>(featT, wt + 0 * 262144, bv + i * CDIM,
                                                 nullptr, nullptr, actA, 0);
        // sampled -> actB
        sample_kernel<<<BN_TOT * NHEADS / 4, 256, 0, stream>>>(refb, offb, awb, actA, actB);
        // attn = sampled @ Wout + bout + q -> tmp (fp32)
        gemm_bf16<<<gemm_grid, 256, 0, stream>>>(actB, wt + 1 * 262144, bout + i * CDIM,
                                                 q, tmp, nullptr, 0);
        // q = LN1(tmp) (fp32 + bf16 copy in actA)
        ln_kernel<<<BN_TOT / 4, 256, 0, stream>>>(tmp, ln1g + i * CDIM, ln1b + i * CDIM, q, actA);
        // h = relu(q @ W1) -> actB (bf16 only)
        gemm_bf16<<<gemm_grid, 256, 0, stream>>>(actA, wt + 2 * 262144, nullptr,
                                                 nullptr, nullptr, actB, 1);
        // ffn = h @ W2 + q -> tmp (fp32)
        gemm_bf16<<<gemm_grid, 256, 0, stream>>>(actB, wt + 3 * 262144, nullptr,
                                                 q, tmp, nullptr, 0);
        // q = LN2(tmp)
        ln_kernel<<<BN_TOT / 4, 256, 0, stream>>>(tmp, ln2g + i * CDIM, ln2b + i * CDIM, q, nullptr);
    }

    // scatter back to dense (B, C, H, W) — overwrites all of d_out
    scatter_kernel<<<dim3(NDIM / 32, CDIM / 32, BDIM), blk328, 0, stream>>>(
        q, order, nvalid, (float*)d_out);
}

// Round 4
// 2459.563 us; speedup vs baseline: 3.3802x; 1.4242x over previous
//
#include <hip/hip_runtime.h>
#include <cstdint>
#include <cstddef>

// Problem constants
#define BDIM 2
#define CDIM 512
#define HDIM 128
#define WDIM 128
#define NDIM (HDIM * WDIM)        // 16384
#define LNUM 6
#define NHEADS 8
#define HEAD_DIM 64
#define NPTS 4
#define BN_TOT (BDIM * NDIM)      // 32768

typedef unsigned short u16;
typedef __attribute__((ext_vector_type(8))) short bf16x8;   // 8 bf16 = 4 VGPRs
typedef __attribute__((ext_vector_type(4))) float f32x4;    // MFMA accum

__device__ __forceinline__ u16 f2bf(float x) {              // RNE fp32->bf16
    unsigned u = __float_as_uint(x);
    u += 0x7fffu + ((u >> 16) & 1u);
    return (u16)(u >> 16);
}
__device__ __forceinline__ float bf2f(u16 h) {
    return __uint_as_float(((unsigned)h) << 16);
}

__device__ __forceinline__ void load_lds16(const void* g, void* l) {
    // async global->LDS, 16B/lane; LDS dest = wave-uniform base + lane*16
    __builtin_amdgcn_global_load_lds(
        (const __attribute__((address_space(1))) void*)g,
        (__attribute__((address_space(3))) void*)l, 16, 0, 0);
}

// ---------------------------------------------------------------------------
// voxelization: mask / order / ref / pack_q  (fp32)
// ---------------------------------------------------------------------------
__global__ void mask_kernel(const float* __restrict__ lidar, int* __restrict__ mask)
{
    int idx = blockIdx.x * blockDim.x + threadIdx.x;
    if (idx >= BN_TOT) return;
    int b = idx / NDIM;
    int n = idx - b * NDIM;
    const float* p = lidar + (size_t)b * CDIM * NDIM + n;
    int ok = 1;
#pragma unroll 8
    for (int c = 0; c < CDIM; ++c)
        ok &= (p[(size_t)c * NDIM] != 0.0f);
    mask[idx] = ok;
}

__global__ void order_kernel(const int* __restrict__ mask, int* __restrict__ order,
                             int* __restrict__ nvalid)
{
    int b = blockIdx.x;
    const int* m = mask + b * NDIM;
    int* ord = order + b * NDIM;
    __shared__ int part[256];
    __shared__ int totalValid;
    int t = threadIdx.x;
    const int CHUNK = NDIM / 256;
    int base = t * CHUNK;
    int cnt = 0;
    for (int i = 0; i < CHUNK; ++i) cnt += m[base + i];
    part[t] = cnt;
    __syncthreads();
    for (int s = 1; s < 256; s <<= 1) {
        int v = (t >= s) ? part[t - s] : 0;
        __syncthreads();
        part[t] += v;
        __syncthreads();
    }
    if (t == 255) { totalValid = part[255]; nvalid[b] = part[255]; }
    __syncthreads();
    int validBefore = (t == 0) ? 0 : part[t - 1];
    int nv = totalValid;
    for (int i = 0; i < CHUNK; ++i) {
        int n = base + i;
        if (m[n]) { ord[validBefore] = n; validBefore++; }
        else      { int invBefore = n - validBefore; ord[nv + invBefore] = n; }
    }
}

__global__ void ref_kernel(const int* __restrict__ order, const int* __restrict__ nvalid,
                           float* __restrict__ ref)
{
    int idx = blockIdx.x * blockDim.x + threadIdx.x;
    if (idx >= BN_TOT) return;
    int b = idx / NDIM;
    int j = idx - b * NDIM;
    int n = order[idx];
    float flag = (j < nvalid[b]) ? 1.0f : 0.0f;
    int hh = n / WDIM;
    int ww = n - hh * WDIM;
    ref[(size_t)idx * 2 + 0] = ((float)ww / (float)WDIM) * flag;
    ref[(size_t)idx * 2 + 1] = ((float)hh / (float)HDIM) * flag;
}

__global__ void pack_q_kernel(const float* __restrict__ lidar, const int* __restrict__ order,
                              const int* __restrict__ nvalid, float* __restrict__ q)
{
    __shared__ float tile[32][33];
    __shared__ int ord_s[32];
    int b  = blockIdx.z;
    int j0 = blockIdx.x * 32;
    int c0 = blockIdx.y * 32;
    int tx = threadIdx.x, ty = threadIdx.y;
    if (ty == 0) ord_s[tx] = order[b * NDIM + j0 + tx];
    __syncthreads();
    const float* src = lidar + (size_t)b * CDIM * NDIM;
#pragma unroll
    for (int k = 0; k < 4; ++k) {
        int cl = ty * 4 + k;
        tile[cl][tx] = src[(size_t)(c0 + cl) * NDIM + ord_s[tx]];
    }
    __syncthreads();
    int nv = nvalid[b];
#pragma unroll
    for (int k = 0; k < 4; ++k) {
        int jl = ty * 4 + k;
        int j = j0 + jl;
        float f = (j < nv) ? 1.0f : 0.0f;
        q[((size_t)b * NDIM + j) * CDIM + c0 + tx] = tile[tx][jl] * f;
    }
}

__global__ void scatter_kernel(const float* __restrict__ q, const int* __restrict__ order,
                               const int* __restrict__ nvalid, float* __restrict__ out)
{
    __shared__ float tile[32][33];
    __shared__ int ord_s[32];
    int b  = blockIdx.z;
    int j0 = blockIdx.x * 32;
    int c0 = blockIdx.y * 32;
    int tx = threadIdx.x, ty = threadIdx.y;
    if (ty == 0) ord_s[tx] = order[b * NDIM + j0 + tx];
    __syncthreads();
    int nv = nvalid[b];
#pragma unroll
    for (int k = 0; k < 4; ++k) {
        int jl = ty * 4 + k;
        int j = j0 + jl;
        float f = (j < nv) ? 1.0f : 0.0f;
        tile[jl][tx] = q[((size_t)b * NDIM + j) * CDIM + c0 + tx] * f;
    }
    __syncthreads();
    float* dst = out + (size_t)b * CDIM * NDIM;
#pragma unroll
    for (int k = 0; k < 4; ++k) {
        int cl = ty * 4 + k;
        dst[(size_t)(c0 + cl) * NDIM + ord_s[tx]] = tile[tx][cl];
    }
}

// ---------------------------------------------------------------------------
// weight transpose-convert: src fp32 [K=512][N=512] -> dst bf16 [N][K]
// ---------------------------------------------------------------------------
__global__ void tconv_kernel(const float* __restrict__ src, u16* __restrict__ dst)
{
    __shared__ float t[32][33];
    int k0 = blockIdx.x * 32, n0 = blockIdx.y * 32;
    int tx = threadIdx.x, ty = threadIdx.y;
#pragma unroll
    for (int j = 0; j < 4; ++j) {
        int kl = ty * 4 + j;
        t[kl][tx] = src[(size_t)(k0 + kl) * 512 + n0 + tx];
    }
    __syncthreads();
#pragma unroll
    for (int j = 0; j < 4; ++j) {
        int nl = ty * 4 + j;
        dst[(size_t)(n0 + nl) * 512 + k0 + tx] = f2bf(t[tx][nl]);
    }
}

// Woff [512][64] + Waw [512][32] -> dst bf16 [96][512] (row n = output col)
__global__ void tconv_offaw_kernel(const float* __restrict__ woff,
                                   const float* __restrict__ waw,
                                   u16* __restrict__ dst)
{
    __shared__ float t[32][33];
    int k0 = blockIdx.x * 32, n0 = blockIdx.y * 32;
    int tx = threadIdx.x, ty = threadIdx.y;
#pragma unroll
    for (int j = 0; j < 4; ++j) {
        int kl = ty * 4 + j;
        int n = n0 + tx;
        float v = (n < 64) ? woff[(size_t)(k0 + kl) * 64 + n]
                           : waw[(size_t)(k0 + kl) * 32 + (n - 64)];
        t[kl][tx] = v;
    }
    __syncthreads();
#pragma unroll
    for (int j = 0; j < 4; ++j) {
        int nl = ty * 4 + j;
        dst[(size_t)(n0 + nl) * 512 + k0 + tx] = f2bf(t[tx][nl]);
    }
}

// bev (B,C,N) fp32 -> featT (B,N,C) bf16
__global__ void bev_conv_kernel(const float* __restrict__ bev, u16* __restrict__ dst)
{
    __shared__ float t[32][33];
    int b  = blockIdx.z;
    int n0 = blockIdx.x * 32;
    int c0 = blockIdx.y * 32;
    int tx = threadIdx.x, ty = threadIdx.y;
    const float* src = bev + (size_t)b * CDIM * NDIM;
#pragma unroll
    for (int j = 0; j < 4; ++j) {
        int cl = ty * 4 + j;
        t[cl][tx] = src[(size_t)(c0 + cl) * NDIM + n0 + tx];
    }
    __syncthreads();
#pragma unroll
    for (int j = 0; j < 4; ++j) {
        int nl = ty * 4 + j;
        dst[((size_t)b * NDIM + n0 + nl) * CDIM + c0 + tx] = f2bf(t[tx][nl]);
    }
}

// ---------------------------------------------------------------------------
// PE hidden: h = relu(BN(ref @ pe_W1))  -> bf16
// ---------------------------------------------------------------------------
__global__ void pe_hidden_kernel(const float* __restrict__ ref, const float* __restrict__ W1,
                                 const float* __restrict__ g, const float* __restrict__ bb,
                                 const float* __restrict__ m, const float* __restrict__ v,
                                 u16* __restrict__ out)
{
    int row = blockIdx.x;
    float r0 = ref[(size_t)row * 2 + 0];
    float r1 = ref[(size_t)row * 2 + 1];
    for (int c = threadIdx.x; c < CDIM; c += blockDim.x) {
        float pe = r0 * W1[c] + r1 * W1[CDIM + c];
        pe = (pe - m[c]) * rsqrtf(v[c] + 1e-5f) * g[c] + bb[c];
        out[(size_t)row * CDIM + c] = f2bf(fmaxf(pe, 0.0f));
    }
}

// ---------------------------------------------------------------------------
// x = q(fp32) + qpos(bf16) -> bf16 ; 8 elements/thread (layer-0 only)
// ---------------------------------------------------------------------------
__global__ void add_bf_kernel(const float* __restrict__ q, const u16* __restrict__ qpos,
                              u16* __restrict__ x)
{
    size_t i = (size_t)blockIdx.x * blockDim.x + threadIdx.x;  // 8-el group
    const float4* qp = (const float4*)q + i * 2;
    float4 a = qp[0], b = qp[1];
    uint4 pv = ((const uint4*)qpos)[i];
    float p0 = bf2f((u16)(pv.x & 0xffff)), p1 = bf2f((u16)(pv.x >> 16));
    float p2 = bf2f((u16)(pv.y & 0xffff)), p3 = bf2f((u16)(pv.y >> 16));
    float p4 = bf2f((u16)(pv.z & 0xffff)), p5 = bf2f((u16)(pv.z >> 16));
    float p6 = bf2f((u16)(pv.w & 0xffff)), p7 = bf2f((u16)(pv.w >> 16));
    uint4 r;
    r.x = (unsigned)f2bf(a.x + p0) | ((unsigned)f2bf(a.y + p1) << 16);
    r.y = (unsigned)f2bf(a.z + p2) | ((unsigned)f2bf(a.w + p3) << 16);
    r.z = (unsigned)f2bf(b.x + p4) | ((unsigned)f2bf(b.y + p5) << 16);
    r.w = (unsigned)f2bf(b.z + p6) | ((unsigned)f2bf(b.w + p7) << 16);
    ((uint4*)x)[i] = r;
}

// ---------------------------------------------------------------------------
// MFMA bf16 GEMM: C[M=32768][512] = A[M][512]bf16 @ Bt[512][512]^T bf16
// ---------------------------------------------------------------------------
__global__ __launch_bounds__(256) void gemm_bf16(
    const u16* __restrict__ A, const u16* __restrict__ Bt,
    const float* __restrict__ bias, const float* __restrict__ resid,
    float* __restrict__ outF, u16* __restrict__ outB, int relu)
{
    __shared__ u16 As[128 * 32];
    __shared__ u16 Bs[128 * 32];
    int tid = threadIdx.x;
    int wave = tid >> 6, lane = tid & 63;
    int wr = wave >> 1, wc = wave & 1;
    int quad = lane >> 4, l15 = lane & 15;
    int bm = blockIdx.y * 128, bn = blockIdx.x * 128;

    f32x4 acc[4][4];
#pragma unroll
    for (int i = 0; i < 4; ++i)
#pragma unroll
        for (int j = 0; j < 4; ++j) { f32x4 z = {0.f, 0.f, 0.f, 0.f}; acc[i][j] = z; }

    int e0 = wave * 512 + lane * 8;
    int e1 = (wave + 4) * 512 + lane * 8;
    const u16* Ag0 = A + (size_t)(bm + (e0 >> 5)) * 512 + (e0 & 31);
    const u16* Ag1 = A + (size_t)(bm + (e1 >> 5)) * 512 + (e1 & 31);
    const u16* Bg0 = Bt + (size_t)(bn + (e0 >> 5)) * 512 + (e0 & 31);
    const u16* Bg1 = Bt + (size_t)(bn + (e1 >> 5)) * 512 + (e1 & 31);

    for (int k0 = 0; k0 < 512; k0 += 32) {
        load_lds16(Ag0 + k0, &As[wave * 512]);
        load_lds16(Ag1 + k0, &As[(wave + 4) * 512]);
        load_lds16(Bg0 + k0, &Bs[wave * 512]);
        load_lds16(Bg1 + k0, &Bs[(wave + 4) * 512]);
        __syncthreads();
        bf16x8 av[4], bv[4];
#pragma unroll
        for (int mi = 0; mi < 4; ++mi)
            av[mi] = *(const bf16x8*)&As[(wr * 64 + mi * 16 + l15) * 32 + quad * 8];
#pragma unroll
        for (int ni = 0; ni < 4; ++ni)
            bv[ni] = *(const bf16x8*)&Bs[(wc * 64 + ni * 16 + l15) * 32 + quad * 8];
#pragma unroll
        for (int mi = 0; mi < 4; ++mi)
#pragma unroll
            for (int ni = 0; ni < 4; ++ni)
                acc[mi][ni] = __builtin_amdgcn_mfma_f32_16x16x32_bf16(
                    av[mi], bv[ni], acc[mi][ni], 0, 0, 0);
        __syncthreads();
    }

    int rowb = bm + wr * 64;
    int colb = bn + wc * 64;
#pragma unroll
    for (int mi = 0; mi < 4; ++mi) {
#pragma unroll
        for (int ni = 0; ni < 4; ++ni) {
            int col = colb + ni * 16 + l15;
            float bi = bias ? bias[col] : 0.0f;
#pragma unroll
            for (int r = 0; r < 4; ++r) {
                int row = rowb + mi * 16 + quad * 4 + r;
                float val = acc[mi][ni][r] + bi;
                size_t o = (size_t)row * 512 + col;
                if (resid) val += resid[o];
                if (relu) val = fmaxf(val, 0.0f);
                if (outF) outF[o] = val;
                if (outB) outB[o] = f2bf(val);
            }
        }
    }
}

// ---------------------------------------------------------------------------
// fused off+aw GEMM: A[M][512]bf16 @ OffAwT[96][512]bf16 -> offb/awb (bf16)
// ---------------------------------------------------------------------------
__global__ __launch_bounds__(256) void gemm_offaw(
    const u16* __restrict__ A, const u16* __restrict__ Bt,
    const float* __restrict__ boff, const float* __restrict__ baw,
    u16* __restrict__ offb, u16* __restrict__ awb)
{
    __shared__ u16 As[128 * 32];
    __shared__ u16 Bs[128 * 32];
    int tid = threadIdx.x;
    int wave = tid >> 6, lane = tid & 63;
    int wr = wave >> 1, wc = wave & 1;
    int quad = lane >> 4, l15 = lane & 15;
    int bm = blockIdx.y * 128;

    f32x4 acc[4][4];
#pragma unroll
    for (int i = 0; i < 4; ++i)
#pragma unroll
        for (int j = 0; j < 4; ++j) { f32x4 z = {0.f, 0.f, 0.f, 0.f}; acc[i][j] = z; }

    int e0 = wave * 512 + lane * 8;
    int e1 = (wave + 4) * 512 + lane * 8;
    int br0 = e0 >> 5; if (br0 > 95) br0 = 95;
    int br1 = e1 >> 5; if (br1 > 95) br1 = 95;
    const u16* Ag0 = A + (size_t)(bm + (e0 >> 5)) * 512 + (e0 & 31);
    const u16* Ag1 = A + (size_t)(bm + (e1 >> 5)) * 512 + (e1 & 31);
    const u16* Bg0 = Bt + (size_t)br0 * 512 + (e0 & 31);
    const u16* Bg1 = Bt + (size_t)br1 * 512 + (e1 & 31);

    for (int k0 = 0; k0 < 512; k0 += 32) {
        load_lds16(Ag0 + k0, &As[wave * 512]);
        load_lds16(Ag1 + k0, &As[(wave + 4) * 512]);
        load_lds16(Bg0 + k0, &Bs[wave * 512]);
        load_lds16(Bg1 + k0, &Bs[(wave + 4) * 512]);
        __syncthreads();
        bf16x8 av[4], bv[4];
#pragma unroll
        for (int mi = 0; mi < 4; ++mi)
            av[mi] = *(const bf16x8*)&As[(wr * 64 + mi * 16 + l15) * 32 + quad * 8];
#pragma unroll
        for (int ni = 0; ni < 4; ++ni)
            bv[ni] = *(const bf16x8*)&Bs[(wc * 64 + ni * 16 + l15) * 32 + quad * 8];
#pragma unroll
        for (int mi = 0; mi < 4; ++mi)
#pragma unroll
            for (int ni = 0; ni < 4; ++ni)
                acc[mi][ni] = __builtin_amdgcn_mfma_f32_16x16x32_bf16(
                    av[mi], bv[ni], acc[mi][ni], 0, 0, 0);
        __syncthreads();
    }

    int rowb = bm + wr * 64;
#pragma unroll
    for (int mi = 0; mi < 4; ++mi) {
#pragma unroll
        for (int ni = 0; ni < 4; ++ni) {
            int col = wc * 64 + ni * 16 + l15;
            if (col < 96) {
                float bi = (col < 64) ? boff[col] : baw[col - 64];
#pragma unroll
                for (int r = 0; r < 4; ++r) {
                    int row = rowb + mi * 16 + quad * 4 + r;
                    float val = acc[mi][ni][r] + bi;
                    if (col < 64) offb[(size_t)row * 64 + col] = f2bf(val);
                    else          awb[(size_t)row * 32 + (col - 64)] = f2bf(val);
                }
            }
        }
    }
}

// ---------------------------------------------------------------------------
// deformable sampling v2: one wave per (b,j); lane = (head = lane>>3,
// 8 channels = (lane&7)*8). Clamp-index + zero-weight (no divergent loads).
// ---------------------------------------------------------------------------
__global__ __launch_bounds__(256) void sample_kernel(
    const float* __restrict__ ref, const u16* __restrict__ off,
    const u16* __restrict__ aw, const u16* __restrict__ v,
    u16* __restrict__ out)
{
    int bj = blockIdx.x * 4 + (threadIdx.x >> 6);   // b*N + j
    int lane = threadIdx.x & 63;
    int h  = lane >> 3;            // head 0..7
    int d8 = (lane & 7) * 8;       // channel block within head
    int b  = bj >> 14;             // bj / NDIM

    float rx = ref[(size_t)bj * 2 + 0];
    float ry = ref[(size_t)bj * 2 + 1];
    uint4 offv = *(const uint4*)(off + (size_t)bj * 64 + h * 8);   // 8 bf16
    uint2 awv  = *(const uint2*)(aw + (size_t)bj * 32 + h * 4);    // 4 bf16

    float l0 = bf2f((u16)(awv.x & 0xffff)), l1 = bf2f((u16)(awv.x >> 16));
    float l2 = bf2f((u16)(awv.y & 0xffff)), l3 = bf2f((u16)(awv.y >> 16));
    float mx = fmaxf(fmaxf(l0, l1), fmaxf(l2, l3));
    float e[4];
    e[0] = expf(l0 - mx); e[1] = expf(l1 - mx);
    e[2] = expf(l2 - mx); e[3] = expf(l3 - mx);
    float inv_es = 1.0f / (e[0] + e[1] + e[2] + e[3]);

    const u16* vb = v + (size_t)b * NDIM * CDIM + h * HEAD_DIM + d8;
    float acc[8] = {0.f, 0.f, 0.f, 0.f, 0.f, 0.f, 0.f, 0.f};
    unsigned ow[4] = {offv.x, offv.y, offv.z, offv.w};

#pragma unroll
    for (int p = 0; p < NPTS; ++p) {
        float ox = bf2f((u16)(ow[p] & 0xffff));
        float oy = bf2f((u16)(ow[p] >> 16));
        float X = rx * (float)WDIM + ox - 0.5f;
        float Y = ry * (float)HDIM + oy - 0.5f;
        float x0f = floorf(X), y0f = floorf(Y);
        float wx = X - x0f, wy = Y - y0f;
        int x0 = (int)x0f, y0 = (int)y0f;
        float ep = e[p];
#pragma unroll
        for (int cy = 0; cy < 2; ++cy) {
            int yy = y0 + cy;
            float wyc = cy ? wy : (1.0f - wy);
            int yin = (yy >= 0) & (yy < HDIM);
            int yc = min(max(yy, 0), HDIM - 1);
#pragma unroll
            for (int cx = 0; cx < 2; ++cx) {
                int xx = x0 + cx;
                float wxc = cx ? wx : (1.0f - wx);
                int xin = (xx >= 0) & (xx < WDIM);
                int xc = min(max(xx, 0), WDIM - 1);
                float wgt = ep * wyc * wxc * (float)(yin & xin);
                uint4 vv = *(const uint4*)(vb + (size_t)(yc * WDIM + xc) * CDIM);
                acc[0] += wgt * bf2f((u16)(vv.x & 0xffff));
                acc[1] += wgt * bf2f((u16)(vv.x >> 16));
                acc[2] += wgt * bf2f((u16)(vv.y & 0xffff));
                acc[3] += wgt * bf2f((u16)(vv.y >> 16));
                acc[4] += wgt * bf2f((u16)(vv.z & 0xffff));
                acc[5] += wgt * bf2f((u16)(vv.z >> 16));
                acc[6] += wgt * bf2f((u16)(vv.w & 0xffff));
                acc[7] += wgt * bf2f((u16)(vv.w >> 16));
            }
        }
    }
    uint4 r;
    r.x = (unsigned)f2bf(acc[0] * inv_es) | ((unsigned)f2bf(acc[1] * inv_es) << 16);
    r.y = (unsigned)f2bf(acc[2] * inv_es) | ((unsigned)f2bf(acc[3] * inv_es) << 16);
    r.z = (unsigned)f2bf(acc[4] * inv_es) | ((unsigned)f2bf(acc[5] * inv_es) << 16);
    r.w = (unsigned)f2bf(acc[6] * inv_es) | ((unsigned)f2bf(acc[7] * inv_es) << 16);
    *(uint4*)(out + (size_t)bj * CDIM + h * HEAD_DIM + d8) = r;
}

// ---------------------------------------------------------------------------
// LayerNorm over C=512; fp32 out + optional bf16 copy (optionally + qpos)
// ---------------------------------------------------------------------------
__global__ __launch_bounds__(256) void ln_kernel(
    const float* __restrict__ in, const float* __restrict__ g,
    const float* __restrict__ bta, float* __restrict__ out,
    u16* __restrict__ outbf, const u16* __restrict__ addq)
{
    int row = blockIdx.x * 4 + (threadIdx.x >> 6);
    int lane = threadIdx.x & 63;
    const float* p = in + (size_t)row * CDIM;
    float4 u = *(const float4*)(p + lane * 4);
    float4 w = *(const float4*)(p + 256 + lane * 4);
    float s = u.x + u.y + u.z + u.w + w.x + w.y + w.z + w.w;
#pragma unroll
    for (int o = 32; o > 0; o >>= 1) s += __shfl_xor(s, o, 64);
    float mu = s * (1.0f / 512.0f);
    float dx, sq = 0.0f;
    dx = u.x - mu; sq += dx * dx;  dx = u.y - mu; sq += dx * dx;
    dx = u.z - mu; sq += dx * dx;  dx = u.w - mu; sq += dx * dx;
    dx = w.x - mu; sq += dx * dx;  dx = w.y - mu; sq += dx * dx;
    dx = w.z - mu; sq += dx * dx;  dx = w.w - mu; sq += dx * dx;
#pragma unroll
    for (int o = 32; o > 0; o >>= 1) sq += __shfl_xor(sq, o, 64);
    float inv = rsqrtf(sq * (1.0f / 512.0f) + 1e-5f);

    int c0 = lane * 4;
    float4 g0 = *(const float4*)(g + c0);
    float4 b0 = *(const float4*)(bta + c0);
    float4 g1 = *(const float4*)(g + 256 + c0);
    float4 b1 = *(const float4*)(bta + 256 + c0);
    float4 r0, r1;
    r0.x = (u.x - mu) * inv * g0.x + b0.x;
    r0.y = (u.y - mu) * inv * g0.y + b0.y;
    r0.z = (u.z - mu) * inv * g0.z + b0.z;
    r0.w = (u.w - mu) * inv * g0.w + b0.w;
    r1.x = (w.x - mu) * inv * g1.x + b1.x;
    r1.y = (w.y - mu) * inv * g1.y + b1.y;
    r1.z = (w.z - mu) * inv * g1.z + b1.z;
    r1.w = (w.w - mu) * inv * g1.w + b1.w;
    float* qo = out + (size_t)row * CDIM;
    *(float4*)(qo + c0) = r0;
    *(float4*)(qo + 256 + c0) = r1;
    if (outbf) {
        float a0 = 0.f, a1 = 0.f, a2 = 0.f, a3 = 0.f;
        float a4 = 0.f, a5 = 0.f, a6 = 0.f, a7 = 0.f;
        if (addq) {
            const u16* qp = addq + (size_t)row * CDIM;
            uint2 v0 = *(const uint2*)(qp + c0);
            uint2 v1 = *(const uint2*)(qp + 256 + c0);
            a0 = bf2f((u16)(v0.x & 0xffff)); a1 = bf2f((u16)(v0.x >> 16));
            a2 = bf2f((u16)(v0.y & 0xffff)); a3 = bf2f((u16)(v0.y >> 16));
            a4 = bf2f((u16)(v1.x & 0xffff)); a5 = bf2f((u16)(v1.x >> 16));
            a6 = bf2f((u16)(v1.y & 0xffff)); a7 = bf2f((u16)(v1.y >> 16));
        }
        u16* qb = outbf + (size_t)row * CDIM;
        uint2 pk0, pk1;
        pk0.x = (unsigned)f2bf(r0.x + a0) | ((unsigned)f2bf(r0.y + a1) << 16);
        pk0.y = (unsigned)f2bf(r0.z + a2) | ((unsigned)f2bf(r0.w + a3) << 16);
        pk1.x = (unsigned)f2bf(r1.x + a4) | ((unsigned)f2bf(r1.y + a5) << 16);
        pk1.y = (unsigned)f2bf(r1.z + a6) | ((unsigned)f2bf(r1.w + a7) << 16);
        *(uint2*)(qb + c0) = pk0;
        *(uint2*)(qb + 256 + c0) = pk1;
    }
}

// ---------------------------------------------------------------------------
// launcher
// ---------------------------------------------------------------------------
extern "C" void kernel_launch(void* const* d_in, const int* in_sizes, int n_in,
                              void* d_out, int out_size, void* d_ws, size_t ws_size,
                              hipStream_t stream)
{
    const float* bev   = (const float*)d_in[0];
    const float* lidar = (const float*)d_in[1];
    const float* Wv    = (const float*)d_in[2];
    const float* bv    = (const float*)d_in[3];
    const float* Woff  = (const float*)d_in[4];
    const float* boff  = (const float*)d_in[5];
    const float* Waw   = (const float*)d_in[6];
    const float* baw   = (const float*)d_in[7];
    const float* Wout  = (const float*)d_in[8];
    const float* bout  = (const float*)d_in[9];
    const float* ln1g  = (const float*)d_in[10];
    const float* ln1b  = (const float*)d_in[11];
    const float* W1    = (const float*)d_in[12];
    const float* W2    = (const float*)d_in[13];
    const float* ln2g  = (const float*)d_in[14];
    const float* ln2b  = (const float*)d_in[15];
    const float* peW1  = (const float*)d_in[16];
    const float* peg   = (const float*)d_in[17];
    const float* peb   = (const float*)d_in[18];
    const float* pem   = (const float*)d_in[19];
    const float* pev   = (const float*)d_in[20];
    const float* peW2  = (const float*)d_in[21];

    const size_t NC = (size_t)BN_TOT * CDIM;    // 16,777,216

    char* base = (char*)d_ws;
    float* q     = (float*)base;                        // NC fp32
    float* tmp   = (float*)(base + NC * 4);             // NC fp32
    u16* actA    = (u16*)(base + NC * 8);               // NC bf16
    u16* actB    = (u16*)(base + NC * 10);              // NC bf16
    u16* wt      = (u16*)(base + NC * 12);              // 4 x 512x512 bf16
    u16* offawt  = wt + 4 * 512 * 512;                  // 96x512 bf16
    u16* offb    = offawt + 96 * 512;                   // BN x 64 bf16
    u16* awb     = offb + (size_t)BN_TOT * 64;          // BN x 32 bf16
    float* refb  = (float*)(awb + (size_t)BN_TOT * 32); // BN x 2 fp32
    int* mask    = (int*)(refb + (size_t)BN_TOT * 2);
    int* order   = mask + BN_TOT;
    int* nvalid  = order + BN_TOT;

    // d_out doubles as scratch until final scatter:
    u16* qpos_bf = (u16*)d_out;                         // NC bf16 (first half)
    u16* featT   = (u16*)d_out + NC;                    // NC bf16 (second half)

    dim3 blk328(32, 8);
    dim3 gemm_grid(4, 256);
    dim3 offaw_grid(1, 256);

    // voxelize
    mask_kernel<<<BN_TOT / 256, 256, 0, stream>>>(lidar, mask);
    order_kernel<<<BDIM, 256, 0, stream>>>(mask, order, nvalid);
    ref_kernel<<<BN_TOT / 256, 256, 0, stream>>>(order, nvalid, refb);
    pack_q_kernel<<<dim3(NDIM / 32, CDIM / 32, BDIM), blk328, 0, stream>>>(lidar, order, nvalid, q);
    bev_conv_kernel<<<dim3(NDIM / 32, CDIM / 32, BDIM), blk328, 0, stream>>>(bev, featT);

    // positional embedding: qpos_bf = relu(BN(ref@peW1)) @ peW2
    pe_hidden_kernel<<<BN_TOT, 128, 0, stream>>>(refb, peW1, peg, peb, pem, pev, actA);
    tconv_kernel<<<dim3(16, 16), blk328, 0, stream>>>(peW2, wt);
    gemm_bf16<<<gemm_grid, 256, 0, stream>>>(actA, wt, nullptr, nullptr,
                                             nullptr, qpos_bf, 0);

    // x0 = q0 + qpos -> actA
    add_bf_kernel<<<(unsigned)(NC / 8 / 256), 256, 0, stream>>>(q, qpos_bf, actA);

    for (int i = 0; i < LNUM; ++i) {
        const size_t WO = (size_t)i * CDIM * CDIM;
        tconv_kernel<<<dim3(16, 16), blk328, 0, stream>>>(Wv + WO,   wt + 0 * 262144);
        tconv_kernel<<<dim3(16, 16), blk328, 0, stream>>>(Wout + WO, wt + 1 * 262144);
        tconv_kernel<<<dim3(16, 16), blk328, 0, stream>>>(W1 + WO,   wt + 2 * 262144);
        tconv_kernel<<<dim3(16, 16), blk328, 0, stream>>>(W2 + WO,   wt + 3 * 262144);
        tconv_offaw_kernel<<<dim3(16, 3), blk328, 0, stream>>>(
            Woff + (size_t)i * CDIM * 64, Waw + (size_t)i * CDIM * 32, offawt);

        // off/aw = x @ [Woff|Waw] + bias  (x in actA)
        gemm_offaw<<<offaw_grid, 256, 0, stream>>>(actA, offawt,
                                                   boff + i * 64, baw + i * 32, offb, awb);
        // v = featT @ Wv + bv -> actA (x dead after offaw)
        gemm_bf16<<<gemm_grid, 256, 0, stream>>>(featT, wt + 0 * 262144, bv + i * CDIM,
                                                 nullptr, nullptr, actA, 0);
        // sampled -> actB
        sample_kernel<<<BN_TOT / 4, 256, 0, stream>>>(refb, offb, awb, actA, actB);
        // attn = sampled @ Wout + bout + q -> tmp (fp32)
        gemm_bf16<<<gemm_grid, 256, 0, stream>>>(actB, wt + 1 * 262144, bout + i * CDIM,
                                                 q, tmp, nullptr, 0);
        // q = LN1(tmp) (fp32 + bf16 copy in actA)
        ln_kernel<<<BN_TOT / 4, 256, 0, stream>>>(tmp, ln1g + i * CDIM, ln1b + i * CDIM,
                                                  q, actA, nullptr);
        // h = relu(q @ W1) -> actB
        gemm_bf16<<<gemm_grid, 256, 0, stream>>>(actA, wt + 2 * 262144, nullptr,
                                                 nullptr, nullptr, actB, 1);
        // ffn = h @ W2 + q -> tmp (fp32)
        gemm_bf16<<<gemm_grid, 256, 0, stream>>>(actB, wt + 3 * 262144, nullptr,
                                                 q, tmp, nullptr, 0);
        // q = LN2(tmp); fused: actA = bf16(q + qpos) = x for next layer
        ln_kernel<<<BN_TOT / 4, 256, 0, stream>>>(tmp, ln2g + i * CDIM, ln2b + i * CDIM,
                                                  q, actA, qpos_bf);
    }

    // scatter back to dense (B, C, H, W) — overwrites all of d_out
    scatter_kernel<<<dim3(NDIM / 32, CDIM / 32, BDIM), blk328, 0, stream>>>(
        q, order, nvalid, (float*)d_out);
}

// Round 5
// 1959.233 us; speedup vs baseline: 4.2434x; 1.2554x over previous
//
#include <hip/hip_runtime.h>
#include <cstdint>
#include <cstddef>

// Problem constants
#define BDIM 2
#define CDIM 512
#define HDIM 128
#define WDIM 128
#define NDIM (HDIM * WDIM)        // 16384
#define LNUM 6
#define NHEADS 8
#define HEAD_DIM 64
#define NPTS 4
#define BN_TOT (BDIM * NDIM)      // 32768

typedef unsigned short u16;
typedef __attribute__((ext_vector_type(8))) short bf16x8;   // 8 bf16 = 4 VGPRs
typedef __attribute__((ext_vector_type(4))) float f32x4;    // MFMA accum

__device__ __forceinline__ u16 f2bf(float x) {              // RNE fp32->bf16
    unsigned u = __float_as_uint(x);
    u += 0x7fffu + ((u >> 16) & 1u);
    return (u16)(u >> 16);
}
__device__ __forceinline__ float bf2f(u16 h) {
    return __uint_as_float(((unsigned)h) << 16);
}

__device__ __forceinline__ void load_lds16(const void* g, void* l) {
    // async global->LDS, 16B/lane; LDS dest = wave-uniform base + lane*16
    __builtin_amdgcn_global_load_lds(
        (const __attribute__((address_space(1))) void*)g,
        (__attribute__((address_space(3))) void*)l, 16, 0, 0);
}

// ---------------------------------------------------------------------------
// voxelization: mask / order / ref / pack_q(bf16)
// ---------------------------------------------------------------------------
__global__ void mask_kernel(const float* __restrict__ lidar, int* __restrict__ mask)
{
    int idx = blockIdx.x * blockDim.x + threadIdx.x;
    if (idx >= BN_TOT) return;
    int b = idx / NDIM;
    int n = idx - b * NDIM;
    const float* p = lidar + (size_t)b * CDIM * NDIM + n;
    int ok = 1;
#pragma unroll 8
    for (int c = 0; c < CDIM; ++c)
        ok &= (p[(size_t)c * NDIM] != 0.0f);
    mask[idx] = ok;
}

__global__ void order_kernel(const int* __restrict__ mask, int* __restrict__ order,
                             int* __restrict__ nvalid)
{
    int b = blockIdx.x;
    const int* m = mask + b * NDIM;
    int* ord = order + b * NDIM;
    __shared__ int part[256];
    __shared__ int totalValid;
    int t = threadIdx.x;
    const int CHUNK = NDIM / 256;
    int base = t * CHUNK;
    int cnt = 0;
    for (int i = 0; i < CHUNK; ++i) cnt += m[base + i];
    part[t] = cnt;
    __syncthreads();
    for (int s = 1; s < 256; s <<= 1) {
        int v = (t >= s) ? part[t - s] : 0;
        __syncthreads();
        part[t] += v;
        __syncthreads();
    }
    if (t == 255) { totalValid = part[255]; nvalid[b] = part[255]; }
    __syncthreads();
    int validBefore = (t == 0) ? 0 : part[t - 1];
    int nv = totalValid;
    for (int i = 0; i < CHUNK; ++i) {
        int n = base + i;
        if (m[n]) { ord[validBefore] = n; validBefore++; }
        else      { int invBefore = n - validBefore; ord[nv + invBefore] = n; }
    }
}

__global__ void ref_kernel(const int* __restrict__ order, const int* __restrict__ nvalid,
                           float* __restrict__ ref)
{
    int idx = blockIdx.x * blockDim.x + threadIdx.x;
    if (idx >= BN_TOT) return;
    int b = idx / NDIM;
    int j = idx - b * NDIM;
    int n = order[idx];
    float flag = (j < nvalid[b]) ? 1.0f : 0.0f;
    int hh = n / WDIM;
    int ww = n - hh * WDIM;
    ref[(size_t)idx * 2 + 0] = ((float)ww / (float)WDIM) * flag;
    ref[(size_t)idx * 2 + 1] = ((float)hh / (float)HDIM) * flag;
}

__global__ void pack_q_kernel(const float* __restrict__ lidar, const int* __restrict__ order,
                              const int* __restrict__ nvalid, u16* __restrict__ q)
{
    __shared__ float tile[32][33];
    __shared__ int ord_s[32];
    int b  = blockIdx.z;
    int j0 = blockIdx.x * 32;
    int c0 = blockIdx.y * 32;
    int tx = threadIdx.x, ty = threadIdx.y;
    if (ty == 0) ord_s[tx] = order[b * NDIM + j0 + tx];
    __syncthreads();
    const float* src = lidar + (size_t)b * CDIM * NDIM;
#pragma unroll
    for (int k = 0; k < 4; ++k) {
        int cl = ty * 4 + k;
        tile[cl][tx] = src[(size_t)(c0 + cl) * NDIM + ord_s[tx]];
    }
    __syncthreads();
    int nv = nvalid[b];
#pragma unroll
    for (int k = 0; k < 4; ++k) {
        int jl = ty * 4 + k;
        int j = j0 + jl;
        float f = (j < nv) ? 1.0f : 0.0f;
        q[((size_t)b * NDIM + j) * CDIM + c0 + tx] = f2bf(tile[tx][jl] * f);
    }
}

// final scatter: out[b,c,order[j]] = q(bf16)[b,j,c] * valid  (fp32 out)
__global__ void scatter_kernel(const u16* __restrict__ q, const int* __restrict__ order,
                               const int* __restrict__ nvalid, float* __restrict__ out)
{
    __shared__ float tile[32][33];
    __shared__ int ord_s[32];
    int b  = blockIdx.z;
    int j0 = blockIdx.x * 32;
    int c0 = blockIdx.y * 32;
    int tx = threadIdx.x, ty = threadIdx.y;
    if (ty == 0) ord_s[tx] = order[b * NDIM + j0 + tx];
    __syncthreads();
    int nv = nvalid[b];
#pragma unroll
    for (int k = 0; k < 4; ++k) {
        int jl = ty * 4 + k;
        int j = j0 + jl;
        float f = (j < nv) ? 1.0f : 0.0f;
        tile[jl][tx] = bf2f(q[((size_t)b * NDIM + j) * CDIM + c0 + tx]) * f;
    }
    __syncthreads();
    float* dst = out + (size_t)b * CDIM * NDIM;
#pragma unroll
    for (int k = 0; k < 4; ++k) {
        int cl = ty * 4 + k;
        dst[(size_t)(c0 + cl) * NDIM + ord_s[tx]] = tile[tx][cl];
    }
}

// ---------------------------------------------------------------------------
// weight transpose-convert: src fp32 [K=512][N=512] -> dst bf16 [N][K]
// ---------------------------------------------------------------------------
__global__ void tconv_kernel(const float* __restrict__ src, u16* __restrict__ dst)
{
    __shared__ float t[32][33];
    int k0 = blockIdx.x * 32, n0 = blockIdx.y * 32;
    int tx = threadIdx.x, ty = threadIdx.y;
#pragma unroll
    for (int j = 0; j < 4; ++j) {
        int kl = ty * 4 + j;
        t[kl][tx] = src[(size_t)(k0 + kl) * 512 + n0 + tx];
    }
    __syncthreads();
#pragma unroll
    for (int j = 0; j < 4; ++j) {
        int nl = ty * 4 + j;
        dst[(size_t)(n0 + nl) * 512 + k0 + tx] = f2bf(t[tx][nl]);
    }
}

// Woff [512][64] + Waw [512][32] -> dst bf16 [96][512]
__global__ void tconv_offaw_kernel(const float* __restrict__ woff,
                                   const float* __restrict__ waw,
                                   u16* __restrict__ dst)
{
    __shared__ float t[32][33];
    int k0 = blockIdx.x * 32, n0 = blockIdx.y * 32;
    int tx = threadIdx.x, ty = threadIdx.y;
#pragma unroll
    for (int j = 0; j < 4; ++j) {
        int kl = ty * 4 + j;
        int n = n0 + tx;
        float v = (n < 64) ? woff[(size_t)(k0 + kl) * 64 + n]
                           : waw[(size_t)(k0 + kl) * 32 + (n - 64)];
        t[kl][tx] = v;
    }
    __syncthreads();
#pragma unroll
    for (int j = 0; j < 4; ++j) {
        int nl = ty * 4 + j;
        dst[(size_t)(n0 + nl) * 512 + k0 + tx] = f2bf(t[tx][nl]);
    }
}

// bev (B,C,N) fp32 -> featT (B,N,C) bf16
__global__ void bev_conv_kernel(const float* __restrict__ bev, u16* __restrict__ dst)
{
    __shared__ float t[32][33];
    int b  = blockIdx.z;
    int n0 = blockIdx.x * 32;
    int c0 = blockIdx.y * 32;
    int tx = threadIdx.x, ty = threadIdx.y;
    const float* src = bev + (size_t)b * CDIM * NDIM;
#pragma unroll
    for (int j = 0; j < 4; ++j) {
        int cl = ty * 4 + j;
        t[cl][tx] = src[(size_t)(c0 + cl) * NDIM + n0 + tx];
    }
    __syncthreads();
#pragma unroll
    for (int j = 0; j < 4; ++j) {
        int nl = ty * 4 + j;
        dst[((size_t)b * NDIM + n0 + nl) * CDIM + c0 + tx] = f2bf(t[tx][nl]);
    }
}

// ---------------------------------------------------------------------------
// PE hidden: h = relu(BN(ref @ pe_W1))  -> bf16
// ---------------------------------------------------------------------------
__global__ void pe_hidden_kernel(const float* __restrict__ ref, const float* __restrict__ W1,
                                 const float* __restrict__ g, const float* __restrict__ bb,
                                 const float* __restrict__ m, const float* __restrict__ v,
                                 u16* __restrict__ out)
{
    int row = blockIdx.x;
    float r0 = ref[(size_t)row * 2 + 0];
    float r1 = ref[(size_t)row * 2 + 1];
    for (int c = threadIdx.x; c < CDIM; c += blockDim.x) {
        float pe = r0 * W1[c] + r1 * W1[CDIM + c];
        pe = (pe - m[c]) * rsqrtf(v[c] + 1e-5f) * g[c] + bb[c];
        out[(size_t)row * CDIM + c] = f2bf(fmaxf(pe, 0.0f));
    }
}

// ---------------------------------------------------------------------------
// x = q(bf16) + qpos(bf16) -> bf16 ; 8 elements/thread (layer-0 only)
// ---------------------------------------------------------------------------
__global__ void add_bf_kernel(const u16* __restrict__ q, const u16* __restrict__ qpos,
                              u16* __restrict__ x)
{
    size_t i = (size_t)blockIdx.x * blockDim.x + threadIdx.x;  // 8-el group
    uint4 qa = ((const uint4*)q)[i];
    uint4 pv = ((const uint4*)qpos)[i];
    unsigned qw[4] = {qa.x, qa.y, qa.z, qa.w};
    unsigned pw[4] = {pv.x, pv.y, pv.z, pv.w};
    unsigned rw[4];
#pragma unroll
    for (int k = 0; k < 4; ++k) {
        float a0 = bf2f((u16)(qw[k] & 0xffff)), a1 = bf2f((u16)(qw[k] >> 16));
        float p0 = bf2f((u16)(pw[k] & 0xffff)), p1 = bf2f((u16)(pw[k] >> 16));
        rw[k] = (unsigned)f2bf(a0 + p0) | ((unsigned)f2bf(a1 + p1) << 16);
    }
    uint4 r; r.x = rw[0]; r.y = rw[1]; r.z = rw[2]; r.w = rw[3];
    ((uint4*)x)[i] = r;
}

// ---------------------------------------------------------------------------
// plain MFMA bf16 GEMM: C[M][512] = A[M][512] @ Bt[512][512]^T, bf16 out
// 128x128 tile, BK=32, 256 threads (4 waves)
// ---------------------------------------------------------------------------
__global__ __launch_bounds__(256) void gemm_bf16(
    const u16* __restrict__ A, const u16* __restrict__ Bt,
    const float* __restrict__ bias, u16* __restrict__ outB, int relu)
{
    __shared__ u16 As[128 * 32];
    __shared__ u16 Bs[128 * 32];
    int tid = threadIdx.x;
    int wave = tid >> 6, lane = tid & 63;
    int wr = wave >> 1, wc = wave & 1;
    int quad = lane >> 4, l15 = lane & 15;
    int bm = blockIdx.y * 128, bn = blockIdx.x * 128;

    f32x4 acc[4][4];
#pragma unroll
    for (int i = 0; i < 4; ++i)
#pragma unroll
        for (int j = 0; j < 4; ++j) { f32x4 z = {0.f, 0.f, 0.f, 0.f}; acc[i][j] = z; }

    int e0 = wave * 512 + lane * 8;
    int e1 = (wave + 4) * 512 + lane * 8;
    const u16* Ag0 = A + (size_t)(bm + (e0 >> 5)) * 512 + (e0 & 31);
    const u16* Ag1 = A + (size_t)(bm + (e1 >> 5)) * 512 + (e1 & 31);
    const u16* Bg0 = Bt + (size_t)(bn + (e0 >> 5)) * 512 + (e0 & 31);
    const u16* Bg1 = Bt + (size_t)(bn + (e1 >> 5)) * 512 + (e1 & 31);

    for (int k0 = 0; k0 < 512; k0 += 32) {
        load_lds16(Ag0 + k0, &As[wave * 512]);
        load_lds16(Ag1 + k0, &As[(wave + 4) * 512]);
        load_lds16(Bg0 + k0, &Bs[wave * 512]);
        load_lds16(Bg1 + k0, &Bs[(wave + 4) * 512]);
        __syncthreads();
        bf16x8 av[4], bv[4];
#pragma unroll
        for (int mi = 0; mi < 4; ++mi)
            av[mi] = *(const bf16x8*)&As[(wr * 64 + mi * 16 + l15) * 32 + quad * 8];
#pragma unroll
        for (int ni = 0; ni < 4; ++ni)
            bv[ni] = *(const bf16x8*)&Bs[(wc * 64 + ni * 16 + l15) * 32 + quad * 8];
#pragma unroll
        for (int mi = 0; mi < 4; ++mi)
#pragma unroll
            for (int ni = 0; ni < 4; ++ni)
                acc[mi][ni] = __builtin_amdgcn_mfma_f32_16x16x32_bf16(
                    av[mi], bv[ni], acc[mi][ni], 0, 0, 0);
        __syncthreads();
    }

    int rowb = bm + wr * 64;
    int colb = bn + wc * 64;
#pragma unroll
    for (int mi = 0; mi < 4; ++mi) {
#pragma unroll
        for (int ni = 0; ni < 4; ++ni) {
            int col = colb + ni * 16 + l15;
            float bi = bias ? bias[col] : 0.0f;
#pragma unroll
            for (int r = 0; r < 4; ++r) {
                int row = rowb + mi * 16 + quad * 4 + r;
                float val = acc[mi][ni][r] + bi;
                if (relu) val = fmaxf(val, 0.0f);
                outB[(size_t)row * 512 + col] = f2bf(val);
            }
        }
    }
}

// ---------------------------------------------------------------------------
// fused GEMM + residual + LayerNorm (+ optional x = LN + qpos):
//   BM=64, BN=512 (full row), 512 threads (8 waves, each 64 rows x 64 cols)
//   q_out = LN(A@Bt^T + bias + resid);  x_out = q_out + qpos (optional)
// ---------------------------------------------------------------------------
__global__ __launch_bounds__(512, 4) void gemm_ln(
    const u16* __restrict__ A, const u16* __restrict__ Bt,
    const float* __restrict__ bias, const u16* __restrict__ resid,
    const float* __restrict__ g, const float* __restrict__ bta,
    u16* __restrict__ outQ, const u16* __restrict__ qpos, u16* __restrict__ outX)
{
    __shared__ u16 As[64 * 32];      // 4 KB
    __shared__ u16 Bs[512 * 32];     // 32 KB
    __shared__ float rs[8][64];      // row sums per wave
    __shared__ float rq[8][64];      // row sum-sq per wave
    __shared__ float muL[64], invL[64];

    int tid = threadIdx.x;
    int wv = tid >> 6, lane = tid & 63;
    int quad = lane >> 4, l15 = lane & 15;
    int bm = blockIdx.x * 64;

    f32x4 acc[4][4];
#pragma unroll
    for (int i = 0; i < 4; ++i)
#pragma unroll
        for (int j = 0; j < 4; ++j) { f32x4 z = {0.f, 0.f, 0.f, 0.f}; acc[i][j] = z; }

    // staging addresses: lane covers 8 u16 (16B); row = seg*16 + lane/4, col = (lane&3)*8
    const u16* Ag = A + (size_t)(bm + wv * 16 + (lane >> 2)) * 512 + (lane & 3) * 8;
    u16* Al = As + wv * 512;
    const u16* Bg[4];
    u16* Bl[4];
#pragma unroll
    for (int it = 0; it < 4; ++it) {
        int s = wv * 4 + it;
        Bg[it] = Bt + (size_t)(s * 16 + (lane >> 2)) * 512 + (lane & 3) * 8;
        Bl[it] = Bs + s * 512;
    }

    for (int k0 = 0; k0 < 512; k0 += 32) {
        if (wv < 4) load_lds16(Ag + k0, Al);
#pragma unroll
        for (int it = 0; it < 4; ++it) load_lds16(Bg[it] + k0, Bl[it]);
        __syncthreads();
        bf16x8 av[4], bv[4];
#pragma unroll
        for (int mi = 0; mi < 4; ++mi)
            av[mi] = *(const bf16x8*)&As[(mi * 16 + l15) * 32 + quad * 8];
#pragma unroll
        for (int ni = 0; ni < 4; ++ni)
            bv[ni] = *(const bf16x8*)&Bs[(wv * 64 + ni * 16 + l15) * 32 + quad * 8];
#pragma unroll
        for (int mi = 0; mi < 4; ++mi)
#pragma unroll
            for (int ni = 0; ni < 4; ++ni)
                acc[mi][ni] = __builtin_amdgcn_mfma_f32_16x16x32_bf16(
                    av[mi], bv[ni], acc[mi][ni], 0, 0, 0);
        __syncthreads();
    }

    // epilogue: val = acc + bias + resid  (kept in acc)
    int colb = wv * 64;
    float biasv[4], gv[4], btv[4];
#pragma unroll
    for (int ni = 0; ni < 4; ++ni) {
        int c = colb + ni * 16 + l15;
        biasv[ni] = bias ? bias[c] : 0.0f;
        gv[ni] = g[c];
        btv[ni] = bta[c];
    }
#pragma unroll
    for (int mi = 0; mi < 4; ++mi) {
#pragma unroll
        for (int r = 0; r < 4; ++r) {
            size_t rowoff = (size_t)(bm + mi * 16 + quad * 4 + r) * 512;
#pragma unroll
            for (int ni = 0; ni < 4; ++ni) {
                int col = colb + ni * 16 + l15;
                acc[mi][ni][r] += biasv[ni] + bf2f(resid[rowoff + col]);
            }
        }
    }
    // row reduction: per (mi,r) sum across ni then across 16 lanes (l15)
#pragma unroll
    for (int mi = 0; mi < 4; ++mi) {
#pragma unroll
        for (int r = 0; r < 4; ++r) {
            float s = acc[mi][0][r] + acc[mi][1][r] + acc[mi][2][r] + acc[mi][3][r];
            float s2 = acc[mi][0][r] * acc[mi][0][r] + acc[mi][1][r] * acc[mi][1][r]
                     + acc[mi][2][r] * acc[mi][2][r] + acc[mi][3][r] * acc[mi][3][r];
#pragma unroll
            for (int m = 1; m < 16; m <<= 1) {
                s  += __shfl_xor(s, m, 64);
                s2 += __shfl_xor(s2, m, 64);
            }
            if (l15 == 0) {
                rs[wv][mi * 16 + quad * 4 + r] = s;
                rq[wv][mi * 16 + quad * 4 + r] = s2;
            }
        }
    }
    __syncthreads();
    if (tid < 64) {
        float s = 0.f, s2 = 0.f;
#pragma unroll
        for (int w = 0; w < 8; ++w) { s += rs[w][tid]; s2 += rq[w][tid]; }
        float mu = s * (1.0f / 512.0f);
        float var = s2 * (1.0f / 512.0f) - mu * mu;
        muL[tid] = mu;
        invL[tid] = rsqrtf(var + 1e-5f);
    }
    __syncthreads();
#pragma unroll
    for (int mi = 0; mi < 4; ++mi) {
#pragma unroll
        for (int r = 0; r < 4; ++r) {
            int lrow = mi * 16 + quad * 4 + r;
            float mu = muL[lrow], iv = invL[lrow];
            size_t rowoff = (size_t)(bm + lrow) * 512;
#pragma unroll
            for (int ni = 0; ni < 4; ++ni) {
                int col = colb + ni * 16 + l15;
                float y = (acc[mi][ni][r] - mu) * iv * gv[ni] + btv[ni];
                outQ[rowoff + col] = f2bf(y);
                if (outX)
                    outX[rowoff + col] = f2bf(y + bf2f(qpos[rowoff + col]));
            }
        }
    }
}

// ---------------------------------------------------------------------------
// fused off+aw GEMM: A[M][512]bf16 @ OffAwT[96][512]bf16 -> offb/awb (bf16)
// ---------------------------------------------------------------------------
__global__ __launch_bounds__(256) void gemm_offaw(
    const u16* __restrict__ A, const u16* __restrict__ Bt,
    const float* __restrict__ boff, const float* __restrict__ baw,
    u16* __restrict__ offb, u16* __restrict__ awb)
{
    __shared__ u16 As[128 * 32];
    __shared__ u16 Bs[128 * 32];
    int tid = threadIdx.x;
    int wave = tid >> 6, lane = tid & 63;
    int wr = wave >> 1, wc = wave & 1;
    int quad = lane >> 4, l15 = lane & 15;
    int bm = blockIdx.y * 128;

    f32x4 acc[4][4];
#pragma unroll
    for (int i = 0; i < 4; ++i)
#pragma unroll
        for (int j = 0; j < 4; ++j) { f32x4 z = {0.f, 0.f, 0.f, 0.f}; acc[i][j] = z; }

    int e0 = wave * 512 + lane * 8;
    int e1 = (wave + 4) * 512 + lane * 8;
    int br0 = e0 >> 5; if (br0 > 95) br0 = 95;
    int br1 = e1 >> 5; if (br1 > 95) br1 = 95;
    const u16* Ag0 = A + (size_t)(bm + (e0 >> 5)) * 512 + (e0 & 31);
    const u16* Ag1 = A + (size_t)(bm + (e1 >> 5)) * 512 + (e1 & 31);
    const u16* Bg0 = Bt + (size_t)br0 * 512 + (e0 & 31);
    const u16* Bg1 = Bt + (size_t)br1 * 512 + (e1 & 31);

    for (int k0 = 0; k0 < 512; k0 += 32) {
        load_lds16(Ag0 + k0, &As[wave * 512]);
        load_lds16(Ag1 + k0, &As[(wave + 4) * 512]);
        load_lds16(Bg0 + k0, &Bs[wave * 512]);
        load_lds16(Bg1 + k0, &Bs[(wave + 4) * 512]);
        __syncthreads();
        bf16x8 av[4], bv[4];
#pragma unroll
        for (int mi = 0; mi < 4; ++mi)
            av[mi] = *(const bf16x8*)&As[(wr * 64 + mi * 16 + l15) * 32 + quad * 8];
#pragma unroll
        for (int ni = 0; ni < 4; ++ni)
            bv[ni] = *(const bf16x8*)&Bs[(wc * 64 + ni * 16 + l15) * 32 + quad * 8];
#pragma unroll
        for (int mi = 0; mi < 4; ++mi)
#pragma unroll
            for (int ni = 0; ni < 4; ++ni)
                acc[mi][ni] = __builtin_amdgcn_mfma_f32_16x16x32_bf16(
                    av[mi], bv[ni], acc[mi][ni], 0, 0, 0);
        __syncthreads();
    }

    int rowb = bm + wr * 64;
#pragma unroll
    for (int mi = 0; mi < 4; ++mi) {
#pragma unroll
        for (int ni = 0; ni < 4; ++ni) {
            int col = wc * 64 + ni * 16 + l15;
            if (col < 96) {
                float bi = (col < 64) ? boff[col] : baw[col - 64];
#pragma unroll
                for (int r = 0; r < 4; ++r) {
                    int row = rowb + mi * 16 + quad * 4 + r;
                    float val = acc[mi][ni][r] + bi;
                    if (col < 64) offb[(size_t)row * 64 + col] = f2bf(val);
                    else          awb[(size_t)row * 32 + (col - 64)] = f2bf(val);
                }
            }
        }
    }
}

// ---------------------------------------------------------------------------
// deformable sampling: one wave per (b,j); lane = (head, 8 channels)
// ---------------------------------------------------------------------------
__global__ __launch_bounds__(256) void sample_kernel(
    const float* __restrict__ ref, const u16* __restrict__ off,
    const u16* __restrict__ aw, const u16* __restrict__ v,
    u16* __restrict__ out)
{
    int bj = blockIdx.x * 4 + (threadIdx.x >> 6);   // b*N + j
    int lane = threadIdx.x & 63;
    int h  = lane >> 3;
    int d8 = (lane & 7) * 8;
    int b  = bj >> 14;

    float rx = ref[(size_t)bj * 2 + 0];
    float ry = ref[(size_t)bj * 2 + 1];
    uint4 offv = *(const uint4*)(off + (size_t)bj * 64 + h * 8);
    uint2 awv  = *(const uint2*)(aw + (size_t)bj * 32 + h * 4);

    float l0 = bf2f((u16)(awv.x & 0xffff)), l1 = bf2f((u16)(awv.x >> 16));
    float l2 = bf2f((u16)(awv.y & 0xffff)), l3 = bf2f((u16)(awv.y >> 16));
    float mx = fmaxf(fmaxf(l0, l1), fmaxf(l2, l3));
    float e[4];
    e[0] = expf(l0 - mx); e[1] = expf(l1 - mx);
    e[2] = expf(l2 - mx); e[3] = expf(l3 - mx);
    float inv_es = 1.0f / (e[0] + e[1] + e[2] + e[3]);

    const u16* vb = v + (size_t)b * NDIM * CDIM + h * HEAD_DIM + d8;
    float acc[8] = {0.f, 0.f, 0.f, 0.f, 0.f, 0.f, 0.f, 0.f};
    unsigned ow[4] = {offv.x, offv.y, offv.z, offv.w};

#pragma unroll
    for (int p = 0; p < NPTS; ++p) {
        float ox = bf2f((u16)(ow[p] & 0xffff));
        float oy = bf2f((u16)(ow[p] >> 16));
        float X = rx * (float)WDIM + ox - 0.5f;
        float Y = ry * (float)HDIM + oy - 0.5f;
        float x0f = floorf(X), y0f = floorf(Y);
        float wx = X - x0f, wy = Y - y0f;
        int x0 = (int)x0f, y0 = (int)y0f;
        float ep = e[p];
#pragma unroll
        for (int cy = 0; cy < 2; ++cy) {
            int yy = y0 + cy;
            float wyc = cy ? wy : (1.0f - wy);
            int yin = (yy >= 0) & (yy < HDIM);
            int yc = min(max(yy, 0), HDIM - 1);
#pragma unroll
            for (int cx = 0; cx < 2; ++cx) {
                int xx = x0 + cx;
                float wxc = cx ? wx : (1.0f - wx);
                int xin = (xx >= 0) & (xx < WDIM);
                int xc = min(max(xx, 0), WDIM - 1);
                float wgt = ep * wyc * wxc * (float)(yin & xin);
                uint4 vv = *(const uint4*)(vb + (size_t)(yc * WDIM + xc) * CDIM);
                acc[0] += wgt * bf2f((u16)(vv.x & 0xffff));
                acc[1] += wgt * bf2f((u16)(vv.x >> 16));
                acc[2] += wgt * bf2f((u16)(vv.y & 0xffff));
                acc[3] += wgt * bf2f((u16)(vv.y >> 16));
                acc[4] += wgt * bf2f((u16)(vv.z & 0xffff));
                acc[5] += wgt * bf2f((u16)(vv.z >> 16));
                acc[6] += wgt * bf2f((u16)(vv.w & 0xffff));
                acc[7] += wgt * bf2f((u16)(vv.w >> 16));
            }
        }
    }
    uint4 r;
    r.x = (unsigned)f2bf(acc[0] * inv_es) | ((unsigned)f2bf(acc[1] * inv_es) << 16);
    r.y = (unsigned)f2bf(acc[2] * inv_es) | ((unsigned)f2bf(acc[3] * inv_es) << 16);
    r.z = (unsigned)f2bf(acc[4] * inv_es) | ((unsigned)f2bf(acc[5] * inv_es) << 16);
    r.w = (unsigned)f2bf(acc[6] * inv_es) | ((unsigned)f2bf(acc[7] * inv_es) << 16);
    *(uint4*)(out + (size_t)bj * CDIM + h * HEAD_DIM + d8) = r;
}

// ---------------------------------------------------------------------------
// launcher
// ---------------------------------------------------------------------------
extern "C" void kernel_launch(void* const* d_in, const int* in_sizes, int n_in,
                              void* d_out, int out_size, void* d_ws, size_t ws_size,
                              hipStream_t stream)
{
    const float* bev   = (const float*)d_in[0];
    const float* lidar = (const float*)d_in[1];
    const float* Wv    = (const float*)d_in[2];
    const float* bv    = (const float*)d_in[3];
    const float* Woff  = (const float*)d_in[4];
    const float* boff  = (const float*)d_in[5];
    const float* Waw   = (const float*)d_in[6];
    const float* baw   = (const float*)d_in[7];
    const float* Wout  = (const float*)d_in[8];
    const float* bout  = (const float*)d_in[9];
    const float* ln1g  = (const float*)d_in[10];
    const float* ln1b  = (const float*)d_in[11];
    const float* W1    = (const float*)d_in[12];
    const float* W2    = (const float*)d_in[13];
    const float* ln2g  = (const float*)d_in[14];
    const float* ln2b  = (const float*)d_in[15];
    const float* peW1  = (const float*)d_in[16];
    const float* peg   = (const float*)d_in[17];
    const float* peb   = (const float*)d_in[18];
    const float* pem   = (const float*)d_in[19];
    const float* pev   = (const float*)d_in[20];
    const float* pevW2 = (const float*)d_in[21];

    const size_t NC = (size_t)BN_TOT * CDIM;    // 16,777,216

    char* base = (char*)d_ws;
    u16* q      = (u16*)base;                           // NC bf16 (residual stream)
    u16* actX   = (u16*)(base + NC * 2);                // NC bf16 (x = q + qpos)
    u16* actA   = (u16*)(base + NC * 4);                // NC bf16 (v / h / pe-hidden)
    u16* actB   = (u16*)(base + NC * 6);                // NC bf16 (sampled)
    u16* wt     = (u16*)(base + NC * 8);                // 4 x 512x512 bf16
    u16* offawt = wt + 4 * 512 * 512;                   // 96x512 bf16
    u16* offb   = offawt + 96 * 512;                    // BN x 64 bf16
    u16* awb    = offb + (size_t)BN_TOT * 64;           // BN x 32 bf16
    float* refb = (float*)(awb + (size_t)BN_TOT * 32);  // BN x 2 fp32
    int* mask   = (int*)(refb + (size_t)BN_TOT * 2);
    int* order  = mask + BN_TOT;
    int* nvalid = order + BN_TOT;

    // d_out doubles as scratch until final scatter:
    u16* qpos_bf = (u16*)d_out;                         // NC bf16 (first half)
    u16* featT   = (u16*)d_out + NC;                    // NC bf16 (second half)

    dim3 blk328(32, 8);
    dim3 gemm_grid(4, 256);        // 128x128 tiles
    dim3 offaw_grid(1, 256);
    int  ln_grid = BN_TOT / 64;    // 512 blocks of 64 rows

    // voxelize
    mask_kernel<<<BN_TOT / 256, 256, 0, stream>>>(lidar, mask);
    order_kernel<<<BDIM, 256, 0, stream>>>(mask, order, nvalid);
    ref_kernel<<<BN_TOT / 256, 256, 0, stream>>>(order, nvalid, refb);
    pack_q_kernel<<<dim3(NDIM / 32, CDIM / 32, BDIM), blk328, 0, stream>>>(lidar, order, nvalid, q);
    bev_conv_kernel<<<dim3(NDIM / 32, CDIM / 32, BDIM), blk328, 0, stream>>>(bev, featT);

    // positional embedding: qpos_bf = relu(BN(ref@peW1)) @ peW2
    pe_hidden_kernel<<<BN_TOT, 128, 0, stream>>>(refb, peW1, peg, peb, pem, pev, actA);
    tconv_kernel<<<dim3(16, 16), blk328, 0, stream>>>(pevW2, wt);
    gemm_bf16<<<gemm_grid, 256, 0, stream>>>(actA, wt, nullptr, qpos_bf, 0);

    // x0 = q0 + qpos -> actX
    add_bf_kernel<<<(unsigned)(NC / 8 / 256), 256, 0, stream>>>(q, qpos_bf, actX);

    for (int i = 0; i < LNUM; ++i) {
        const size_t WO = (size_t)i * CDIM * CDIM;
        tconv_kernel<<<dim3(16, 16), blk328, 0, stream>>>(Wv + WO,   wt + 0 * 262144);
        tconv_kernel<<<dim3(16, 16), blk328, 0, stream>>>(Wout + WO, wt + 1 * 262144);
        tconv_kernel<<<dim3(16, 16), blk328, 0, stream>>>(W1 + WO,   wt + 2 * 262144);
        tconv_kernel<<<dim3(16, 16), blk328, 0, stream>>>(W2 + WO,   wt + 3 * 262144);
        tconv_offaw_kernel<<<dim3(16, 3), blk328, 0, stream>>>(
            Woff + (size_t)i * CDIM * 64, Waw + (size_t)i * CDIM * 32, offawt);

        // off/aw = x @ [Woff|Waw] + bias
        gemm_offaw<<<offaw_grid, 256, 0, stream>>>(actX, offawt,
                                                   boff + i * 64, baw + i * 32, offb, awb);
        // v = featT @ Wv + bv -> actA
        gemm_bf16<<<gemm_grid, 256, 0, stream>>>(featT, wt + 0 * 262144, bv + i * CDIM,
                                                 actA, 0);
        // sampled -> actB
        sample_kernel<<<BN_TOT / 4, 256, 0, stream>>>(refb, offb, awb, actA, actB);
        // q = LN1(sampled @ Wout + bout + q)
        gemm_ln<<<ln_grid, 512, 0, stream>>>(actB, wt + 1 * 262144, bout + i * CDIM,
                                             q, ln1g + i * CDIM, ln1b + i * CDIM,
                                             q, nullptr, nullptr);
        // h = relu(q @ W1) -> actA
        gemm_bf16<<<gemm_grid, 256, 0, stream>>>(q, wt + 2 * 262144, nullptr, actA, 1);
        // q = LN2(h @ W2 + q); x = q + qpos -> actX (skip on last layer)
        gemm_ln<<<ln_grid, 512, 0, stream>>>(actA, wt + 3 * 262144, nullptr,
                                             q, ln2g + i * CDIM, ln2b + i * CDIM,
                                             q, qpos_bf,
                                             (i < LNUM - 1) ? actX : nullptr);
    }

    // scatter back to dense (B, C, H, W) — overwrites all of d_out
    scatter_kernel<<<dim3(NDIM / 32, CDIM / 32, BDIM), blk328, 0, stream>>>(
        q, order, nvalid, (float*)d_out);
}

// Round 6
// 1835.417 us; speedup vs baseline: 4.5297x; 1.0675x over previous
//
#include <hip/hip_runtime.h>
#include <cstdint>
#include <cstddef>

// Problem constants
#define BDIM 2
#define CDIM 512
#define HDIM 128
#define WDIM 128
#define NDIM (HDIM * WDIM)        // 16384
#define LNUM 6
#define NHEADS 8
#define HEAD_DIM 64
#define NPTS 4
#define BN_TOT (BDIM * NDIM)      // 32768

typedef unsigned short u16;
typedef __attribute__((ext_vector_type(8))) short bf16x8;   // 8 bf16 = 4 VGPRs
typedef __attribute__((ext_vector_type(4))) float f32x4;    // MFMA accum

__device__ __forceinline__ u16 f2bf(float x) {              // RNE fp32->bf16
    unsigned u = __float_as_uint(x);
    u += 0x7fffu + ((u >> 16) & 1u);
    return (u16)(u >> 16);
}
__device__ __forceinline__ float bf2f(u16 h) {
    return __uint_as_float(((unsigned)h) << 16);
}

__device__ __forceinline__ void load_lds16(const void* g, void* l) {
    // async global->LDS, 16B/lane; LDS dest = wave-uniform base + lane*16
    __builtin_amdgcn_global_load_lds(
        (const __attribute__((address_space(1))) void*)g,
        (__attribute__((address_space(3))) void*)l, 16, 0, 0);
}

// ---------------------------------------------------------------------------
// voxelization: mask / order / ref / pack_q(bf16)
// ---------------------------------------------------------------------------
__global__ void mask_kernel(const float* __restrict__ lidar, int* __restrict__ mask)
{
    int idx = blockIdx.x * blockDim.x + threadIdx.x;
    if (idx >= BN_TOT) return;
    int b = idx / NDIM;
    int n = idx - b * NDIM;
    const float* p = lidar + (size_t)b * CDIM * NDIM + n;
    int ok = 1;
#pragma unroll 8
    for (int c = 0; c < CDIM; ++c)
        ok &= (p[(size_t)c * NDIM] != 0.0f);
    mask[idx] = ok;
}

__global__ void order_kernel(const int* __restrict__ mask, int* __restrict__ order,
                             int* __restrict__ nvalid)
{
    int b = blockIdx.x;
    const int* m = mask + b * NDIM;
    int* ord = order + b * NDIM;
    __shared__ int part[256];
    __shared__ int totalValid;
    int t = threadIdx.x;
    const int CHUNK = NDIM / 256;
    int base = t * CHUNK;
    int cnt = 0;
    for (int i = 0; i < CHUNK; ++i) cnt += m[base + i];
    part[t] = cnt;
    __syncthreads();
    for (int s = 1; s < 256; s <<= 1) {
        int v = (t >= s) ? part[t - s] : 0;
        __syncthreads();
        part[t] += v;
        __syncthreads();
    }
    if (t == 255) { totalValid = part[255]; nvalid[b] = part[255]; }
    __syncthreads();
    int validBefore = (t == 0) ? 0 : part[t - 1];
    int nv = totalValid;
    for (int i = 0; i < CHUNK; ++i) {
        int n = base + i;
        if (m[n]) { ord[validBefore] = n; validBefore++; }
        else      { int invBefore = n - validBefore; ord[nv + invBefore] = n; }
    }
}

__global__ void ref_kernel(const int* __restrict__ order, const int* __restrict__ nvalid,
                           float* __restrict__ ref)
{
    int idx = blockIdx.x * blockDim.x + threadIdx.x;
    if (idx >= BN_TOT) return;
    int b = idx / NDIM;
    int j = idx - b * NDIM;
    int n = order[idx];
    float flag = (j < nvalid[b]) ? 1.0f : 0.0f;
    int hh = n / WDIM;
    int ww = n - hh * WDIM;
    ref[(size_t)idx * 2 + 0] = ((float)ww / (float)WDIM) * flag;
    ref[(size_t)idx * 2 + 1] = ((float)hh / (float)HDIM) * flag;
}

__global__ void pack_q_kernel(const float* __restrict__ lidar, const int* __restrict__ order,
                              const int* __restrict__ nvalid, u16* __restrict__ q)
{
    __shared__ float tile[32][33];
    __shared__ int ord_s[32];
    int b  = blockIdx.z;
    int j0 = blockIdx.x * 32;
    int c0 = blockIdx.y * 32;
    int tx = threadIdx.x, ty = threadIdx.y;
    if (ty == 0) ord_s[tx] = order[b * NDIM + j0 + tx];
    __syncthreads();
    const float* src = lidar + (size_t)b * CDIM * NDIM;
#pragma unroll
    for (int k = 0; k < 4; ++k) {
        int cl = ty * 4 + k;
        tile[cl][tx] = src[(size_t)(c0 + cl) * NDIM + ord_s[tx]];
    }
    __syncthreads();
    int nv = nvalid[b];
#pragma unroll
    for (int k = 0; k < 4; ++k) {
        int jl = ty * 4 + k;
        int j = j0 + jl;
        float f = (j < nv) ? 1.0f : 0.0f;
        q[((size_t)b * NDIM + j) * CDIM + c0 + tx] = f2bf(tile[tx][jl] * f);
    }
}

// final scatter: out[b,c,order[j]] = q(bf16)[b,j,c] * valid  (fp32 out)
__global__ void scatter_kernel(const u16* __restrict__ q, const int* __restrict__ order,
                               const int* __restrict__ nvalid, float* __restrict__ out)
{
    __shared__ float tile[32][33];
    __shared__ int ord_s[32];
    int b  = blockIdx.z;
    int j0 = blockIdx.x * 32;
    int c0 = blockIdx.y * 32;
    int tx = threadIdx.x, ty = threadIdx.y;
    if (ty == 0) ord_s[tx] = order[b * NDIM + j0 + tx];
    __syncthreads();
    int nv = nvalid[b];
#pragma unroll
    for (int k = 0; k < 4; ++k) {
        int jl = ty * 4 + k;
        int j = j0 + jl;
        float f = (j < nv) ? 1.0f : 0.0f;
        tile[jl][tx] = bf2f(q[((size_t)b * NDIM + j) * CDIM + c0 + tx]) * f;
    }
    __syncthreads();
    float* dst = out + (size_t)b * CDIM * NDIM;
#pragma unroll
    for (int k = 0; k < 4; ++k) {
        int cl = ty * 4 + k;
        dst[(size_t)(c0 + cl) * NDIM + ord_s[tx]] = tile[tx][cl];
    }
}

// ---------------------------------------------------------------------------
// batched weight transpose-convert: src fp32 [z][512][512] -> dst bf16 [z][N][K]
// ---------------------------------------------------------------------------
__global__ void tconv_b_kernel(const float* __restrict__ src0, u16* __restrict__ dst0)
{
    __shared__ float t[32][33];
    int z = blockIdx.z;
    const float* src = src0 + (size_t)z * 512 * 512;
    u16* dst = dst0 + (size_t)z * 512 * 512;
    int k0 = blockIdx.x * 32, n0 = blockIdx.y * 32;
    int tx = threadIdx.x, ty = threadIdx.y;
#pragma unroll
    for (int j = 0; j < 4; ++j) {
        int kl = ty * 4 + j;
        t[kl][tx] = src[(size_t)(k0 + kl) * 512 + n0 + tx];
    }
    __syncthreads();
#pragma unroll
    for (int j = 0; j < 4; ++j) {
        int nl = ty * 4 + j;
        dst[(size_t)(n0 + nl) * 512 + k0 + tx] = f2bf(t[tx][nl]);
    }
}

// batched: Woff [z][512][64] + Waw [z][512][32] -> dst bf16 [z][96][512]
__global__ void tconv_offaw_b_kernel(const float* __restrict__ woff0,
                                     const float* __restrict__ waw0,
                                     u16* __restrict__ dst0)
{
    __shared__ float t[32][33];
    int z = blockIdx.z;
    const float* woff = woff0 + (size_t)z * 512 * 64;
    const float* waw  = waw0 + (size_t)z * 512 * 32;
    u16* dst = dst0 + (size_t)z * 96 * 512;
    int k0 = blockIdx.x * 32, n0 = blockIdx.y * 32;
    int tx = threadIdx.x, ty = threadIdx.y;
#pragma unroll
    for (int j = 0; j < 4; ++j) {
        int kl = ty * 4 + j;
        int n = n0 + tx;
        float v = (n < 64) ? woff[(size_t)(k0 + kl) * 64 + n]
                           : waw[(size_t)(k0 + kl) * 32 + (n - 64)];
        t[kl][tx] = v;
    }
    __syncthreads();
#pragma unroll
    for (int j = 0; j < 4; ++j) {
        int nl = ty * 4 + j;
        dst[(size_t)(n0 + nl) * 512 + k0 + tx] = f2bf(t[tx][nl]);
    }
}

// bev (B,C,N) fp32 -> featT (B,N,C) bf16
__global__ void bev_conv_kernel(const float* __restrict__ bev, u16* __restrict__ dst)
{
    __shared__ float t[32][33];
    int b  = blockIdx.z;
    int n0 = blockIdx.x * 32;
    int c0 = blockIdx.y * 32;
    int tx = threadIdx.x, ty = threadIdx.y;
    const float* src = bev + (size_t)b * CDIM * NDIM;
#pragma unroll
    for (int j = 0; j < 4; ++j) {
        int cl = ty * 4 + j;
        t[cl][tx] = src[(size_t)(c0 + cl) * NDIM + n0 + tx];
    }
    __syncthreads();
#pragma unroll
    for (int j = 0; j < 4; ++j) {
        int nl = ty * 4 + j;
        dst[((size_t)b * NDIM + n0 + nl) * CDIM + c0 + tx] = f2bf(t[tx][nl]);
    }
}

// ---------------------------------------------------------------------------
// PE hidden: h = relu(BN(ref @ pe_W1))  -> bf16
// ---------------------------------------------------------------------------
__global__ void pe_hidden_kernel(const float* __restrict__ ref, const float* __restrict__ W1,
                                 const float* __restrict__ g, const float* __restrict__ bb,
                                 const float* __restrict__ m, const float* __restrict__ v,
                                 u16* __restrict__ out)
{
    int row = blockIdx.x;
    float r0 = ref[(size_t)row * 2 + 0];
    float r1 = ref[(size_t)row * 2 + 1];
    for (int c = threadIdx.x; c < CDIM; c += blockDim.x) {
        float pe = r0 * W1[c] + r1 * W1[CDIM + c];
        pe = (pe - m[c]) * rsqrtf(v[c] + 1e-5f) * g[c] + bb[c];
        out[(size_t)row * CDIM + c] = f2bf(fmaxf(pe, 0.0f));
    }
}

// ---------------------------------------------------------------------------
// x = q(bf16) + qpos(bf16) -> bf16 ; 8 elements/thread (layer-0 only)
// ---------------------------------------------------------------------------
__global__ void add_bf_kernel(const u16* __restrict__ q, const u16* __restrict__ qpos,
                              u16* __restrict__ x)
{
    size_t i = (size_t)blockIdx.x * blockDim.x + threadIdx.x;  // 8-el group
    uint4 qa = ((const uint4*)q)[i];
    uint4 pv = ((const uint4*)qpos)[i];
    unsigned qw[4] = {qa.x, qa.y, qa.z, qa.w};
    unsigned pw[4] = {pv.x, pv.y, pv.z, pv.w};
    unsigned rw[4];
#pragma unroll
    for (int k = 0; k < 4; ++k) {
        float a0 = bf2f((u16)(qw[k] & 0xffff)), a1 = bf2f((u16)(qw[k] >> 16));
        float p0 = bf2f((u16)(pw[k] & 0xffff)), p1 = bf2f((u16)(pw[k] >> 16));
        rw[k] = (unsigned)f2bf(a0 + p0) | ((unsigned)f2bf(a1 + p1) << 16);
    }
    uint4 r; r.x = rw[0]; r.y = rw[1]; r.z = rw[2]; r.w = rw[3];
    ((uint4*)x)[i] = r;
}

// ---------------------------------------------------------------------------
// plain MFMA bf16 GEMM, double-buffered LDS:
// C[M][512] = A[M][512] @ Bt[512][512]^T, bf16 out. 128x128 tile, BK=32.
// ---------------------------------------------------------------------------
__global__ __launch_bounds__(256) void gemm_bf16(
    const u16* __restrict__ A, const u16* __restrict__ Bt,
    const float* __restrict__ bias, u16* __restrict__ outB, int relu)
{
    __shared__ u16 As[2][128 * 32];
    __shared__ u16 Bs[2][128 * 32];
    int tid = threadIdx.x;
    int wave = tid >> 6, lane = tid & 63;
    int wr = wave >> 1, wc = wave & 1;
    int quad = lane >> 4, l15 = lane & 15;
    int bm = blockIdx.y * 128, bn = blockIdx.x * 128;

    f32x4 acc[4][4];
#pragma unroll
    for (int i = 0; i < 4; ++i)
#pragma unroll
        for (int j = 0; j < 4; ++j) { f32x4 z = {0.f, 0.f, 0.f, 0.f}; acc[i][j] = z; }

    int e0 = wave * 512 + lane * 8;
    int e1 = (wave + 4) * 512 + lane * 8;
    const u16* Ag0 = A + (size_t)(bm + (e0 >> 5)) * 512 + (e0 & 31);
    const u16* Ag1 = A + (size_t)(bm + (e1 >> 5)) * 512 + (e1 & 31);
    const u16* Bg0 = Bt + (size_t)(bn + (e0 >> 5)) * 512 + (e0 & 31);
    const u16* Bg1 = Bt + (size_t)(bn + (e1 >> 5)) * 512 + (e1 & 31);

    // prologue: stage k=0 into buffer 0
    load_lds16(Ag0, &As[0][wave * 512]);
    load_lds16(Ag1, &As[0][(wave + 4) * 512]);
    load_lds16(Bg0, &Bs[0][wave * 512]);
    load_lds16(Bg1, &Bs[0][(wave + 4) * 512]);

    for (int it = 0; it < 16; ++it) {
        __syncthreads();                    // waits current buffer's DMA (vmcnt drain)
        int cur = it & 1, nxt = cur ^ 1;
        if (it < 15) {                      // prefetch next tile; lands during MFMA phase
            int kn = (it + 1) * 32;
            load_lds16(Ag0 + kn, &As[nxt][wave * 512]);
            load_lds16(Ag1 + kn, &As[nxt][(wave + 4) * 512]);
            load_lds16(Bg0 + kn, &Bs[nxt][wave * 512]);
            load_lds16(Bg1 + kn, &Bs[nxt][(wave + 4) * 512]);
        }
        bf16x8 av[4], bv[4];
#pragma unroll
        for (int mi = 0; mi < 4; ++mi)
            av[mi] = *(const bf16x8*)&As[cur][(wr * 64 + mi * 16 + l15) * 32 + quad * 8];
#pragma unroll
        for (int ni = 0; ni < 4; ++ni)
            bv[ni] = *(const bf16x8*)&Bs[cur][(wc * 64 + ni * 16 + l15) * 32 + quad * 8];
#pragma unroll
        for (int mi = 0; mi < 4; ++mi)
#pragma unroll
            for (int ni = 0; ni < 4; ++ni)
                acc[mi][ni] = __builtin_amdgcn_mfma_f32_16x16x32_bf16(
                    av[mi], bv[ni], acc[mi][ni], 0, 0, 0);
    }

    int rowb = bm + wr * 64;
    int colb = bn + wc * 64;
#pragma unroll
    for (int mi = 0; mi < 4; ++mi) {
#pragma unroll
        for (int ni = 0; ni < 4; ++ni) {
            int col = colb + ni * 16 + l15;
            float bi = bias ? bias[col] : 0.0f;
#pragma unroll
            for (int r = 0; r < 4; ++r) {
                int row = rowb + mi * 16 + quad * 4 + r;
                float val = acc[mi][ni][r] + bi;
                if (relu) val = fmaxf(val, 0.0f);
                outB[(size_t)row * 512 + col] = f2bf(val);
            }
        }
    }
}

// ---------------------------------------------------------------------------
// fused GEMM + residual + LayerNorm (+ optional x = LN + qpos), double-buffered:
//   BM=64, BN=512 (full row), 512 threads (8 waves)
// ---------------------------------------------------------------------------
__global__ __launch_bounds__(512, 4) void gemm_ln(
    const u16* __restrict__ A, const u16* __restrict__ Bt,
    const float* __restrict__ bias, const u16* __restrict__ resid,
    const float* __restrict__ g, const float* __restrict__ bta,
    u16* __restrict__ outQ, const u16* __restrict__ qpos, u16* __restrict__ outX)
{
    __shared__ u16 As[2][64 * 32];       // 8 KB
    __shared__ u16 Bs[2][512 * 32];      // 64 KB
    __shared__ float rs[8][64];
    __shared__ float rq[8][64];
    __shared__ float muL[64], invL[64];

    int tid = threadIdx.x;
    int wv = tid >> 6, lane = tid & 63;
    int quad = lane >> 4, l15 = lane & 15;
    int bm = blockIdx.x * 64;

    f32x4 acc[4][4];
#pragma unroll
    for (int i = 0; i < 4; ++i)
#pragma unroll
        for (int j = 0; j < 4; ++j) { f32x4 z = {0.f, 0.f, 0.f, 0.f}; acc[i][j] = z; }

    const u16* Ag = A + (size_t)(bm + wv * 16 + (lane >> 2)) * 512 + (lane & 3) * 8;
    const u16* Bg[4];
#pragma unroll
    for (int it = 0; it < 4; ++it) {
        int s = wv * 4 + it;
        Bg[it] = Bt + (size_t)(s * 16 + (lane >> 2)) * 512 + (lane & 3) * 8;
    }

    // prologue: stage k=0 into buffer 0
    if (wv < 4) load_lds16(Ag, &As[0][wv * 512]);
#pragma unroll
    for (int it = 0; it < 4; ++it) load_lds16(Bg[it], &Bs[0][(wv * 4 + it) * 512]);

    for (int kk = 0; kk < 16; ++kk) {
        __syncthreads();
        int cur = kk & 1, nxt = cur ^ 1;
        if (kk < 15) {
            int kn = (kk + 1) * 32;
            if (wv < 4) load_lds16(Ag + kn, &As[nxt][wv * 512]);
#pragma unroll
            for (int it = 0; it < 4; ++it)
                load_lds16(Bg[it] + kn, &Bs[nxt][(wv * 4 + it) * 512]);
        }
        bf16x8 av[4], bv[4];
#pragma unroll
        for (int mi = 0; mi < 4; ++mi)
            av[mi] = *(const bf16x8*)&As[cur][(mi * 16 + l15) * 32 + quad * 8];
#pragma unroll
        for (int ni = 0; ni < 4; ++ni)
            bv[ni] = *(const bf16x8*)&Bs[cur][(wv * 64 + ni * 16 + l15) * 32 + quad * 8];
#pragma unroll
        for (int mi = 0; mi < 4; ++mi)
#pragma unroll
            for (int ni = 0; ni < 4; ++ni)
                acc[mi][ni] = __builtin_amdgcn_mfma_f32_16x16x32_bf16(
                    av[mi], bv[ni], acc[mi][ni], 0, 0, 0);
    }

    // epilogue: val = acc + bias + resid
    int colb = wv * 64;
    float biasv[4], gv[4], btv[4];
#pragma unroll
    for (int ni = 0; ni < 4; ++ni) {
        int c = colb + ni * 16 + l15;
        biasv[ni] = bias ? bias[c] : 0.0f;
        gv[ni] = g[c];
        btv[ni] = bta[c];
    }
#pragma unroll
    for (int mi = 0; mi < 4; ++mi) {
#pragma unroll
        for (int r = 0; r < 4; ++r) {
            size_t rowoff = (size_t)(bm + mi * 16 + quad * 4 + r) * 512;
#pragma unroll
            for (int ni = 0; ni < 4; ++ni) {
                int col = colb + ni * 16 + l15;
                acc[mi][ni][r] += biasv[ni] + bf2f(resid[rowoff + col]);
            }
        }
    }
    // row reduction: per (mi,r) sum across ni then across 16 lanes
#pragma unroll
    for (int mi = 0; mi < 4; ++mi) {
#pragma unroll
        for (int r = 0; r < 4; ++r) {
            float s = acc[mi][0][r] + acc[mi][1][r] + acc[mi][2][r] + acc[mi][3][r];
            float s2 = acc[mi][0][r] * acc[mi][0][r] + acc[mi][1][r] * acc[mi][1][r]
                     + acc[mi][2][r] * acc[mi][2][r] + acc[mi][3][r] * acc[mi][3][r];
#pragma unroll
            for (int m = 1; m < 16; m <<= 1) {
                s  += __shfl_xor(s, m, 64);
                s2 += __shfl_xor(s2, m, 64);
            }
            if (l15 == 0) {
                rs[wv][mi * 16 + quad * 4 + r] = s;
                rq[wv][mi * 16 + quad * 4 + r] = s2;
            }
        }
    }
    __syncthreads();
    if (tid < 64) {
        float s = 0.f, s2 = 0.f;
#pragma unroll
        for (int w = 0; w < 8; ++w) { s += rs[w][tid]; s2 += rq[w][tid]; }
        float mu = s * (1.0f / 512.0f);
        float var = s2 * (1.0f / 512.0f) - mu * mu;
        muL[tid] = mu;
        invL[tid] = rsqrtf(var + 1e-5f);
    }
    __syncthreads();
#pragma unroll
    for (int mi = 0; mi < 4; ++mi) {
#pragma unroll
        for (int r = 0; r < 4; ++r) {
            int lrow = mi * 16 + quad * 4 + r;
            float mu = muL[lrow], iv = invL[lrow];
            size_t rowoff = (size_t)(bm + lrow) * 512;
#pragma unroll
            for (int ni = 0; ni < 4; ++ni) {
                int col = colb + ni * 16 + l15;
                float y = (acc[mi][ni][r] - mu) * iv * gv[ni] + btv[ni];
                outQ[rowoff + col] = f2bf(y);
                if (outX)
                    outX[rowoff + col] = f2bf(y + bf2f(qpos[rowoff + col]));
            }
        }
    }
}

// ---------------------------------------------------------------------------
// fused off+aw GEMM, double-buffered: A @ OffAwT[96][512] -> offb/awb (bf16)
// ---------------------------------------------------------------------------
__global__ __launch_bounds__(256) void gemm_offaw(
    const u16* __restrict__ A, const u16* __restrict__ Bt,
    const float* __restrict__ boff, const float* __restrict__ baw,
    u16* __restrict__ offb, u16* __restrict__ awb)
{
    __shared__ u16 As[2][128 * 32];
    __shared__ u16 Bs[2][128 * 32];
    int tid = threadIdx.x;
    int wave = tid >> 6, lane = tid & 63;
    int wr = wave >> 1, wc = wave & 1;
    int quad = lane >> 4, l15 = lane & 15;
    int bm = blockIdx.y * 128;

    f32x4 acc[4][4];
#pragma unroll
    for (int i = 0; i < 4; ++i)
#pragma unroll
        for (int j = 0; j < 4; ++j) { f32x4 z = {0.f, 0.f, 0.f, 0.f}; acc[i][j] = z; }

    int e0 = wave * 512 + lane * 8;
    int e1 = (wave + 4) * 512 + lane * 8;
    int br0 = e0 >> 5; if (br0 > 95) br0 = 95;
    int br1 = e1 >> 5; if (br1 > 95) br1 = 95;
    const u16* Ag0 = A + (size_t)(bm + (e0 >> 5)) * 512 + (e0 & 31);
    const u16* Ag1 = A + (size_t)(bm + (e1 >> 5)) * 512 + (e1 & 31);
    const u16* Bg0 = Bt + (size_t)br0 * 512 + (e0 & 31);
    const u16* Bg1 = Bt + (size_t)br1 * 512 + (e1 & 31);

    load_lds16(Ag0, &As[0][wave * 512]);
    load_lds16(Ag1, &As[0][(wave + 4) * 512]);
    load_lds16(Bg0, &Bs[0][wave * 512]);
    load_lds16(Bg1, &Bs[0][(wave + 4) * 512]);

    for (int it = 0; it < 16; ++it) {
        __syncthreads();
        int cur = it & 1, nxt = cur ^ 1;
        if (it < 15) {
            int kn = (it + 1) * 32;
            load_lds16(Ag0 + kn, &As[nxt][wave * 512]);
            load_lds16(Ag1 + kn, &As[nxt][(wave + 4) * 512]);
            load_lds16(Bg0 + kn, &Bs[nxt][wave * 512]);
            load_lds16(Bg1 + kn, &Bs[nxt][(wave + 4) * 512]);
        }
        bf16x8 av[4], bv[4];
#pragma unroll
        for (int mi = 0; mi < 4; ++mi)
            av[mi] = *(const bf16x8*)&As[cur][(wr * 64 + mi * 16 + l15) * 32 + quad * 8];
#pragma unroll
        for (int ni = 0; ni < 4; ++ni)
            bv[ni] = *(const bf16x8*)&Bs[cur][(wc * 64 + ni * 16 + l15) * 32 + quad * 8];
#pragma unroll
        for (int mi = 0; mi < 4; ++mi)
#pragma unroll
            for (int ni = 0; ni < 4; ++ni)
                acc[mi][ni] = __builtin_amdgcn_mfma_f32_16x16x32_bf16(
                    av[mi], bv[ni], acc[mi][ni], 0, 0, 0);
    }

    int rowb = bm + wr * 64;
#pragma unroll
    for (int mi = 0; mi < 4; ++mi) {
#pragma unroll
        for (int ni = 0; ni < 4; ++ni) {
            int col = wc * 64 + ni * 16 + l15;
            if (col < 96) {
                float bi = (col < 64) ? boff[col] : baw[col - 64];
#pragma unroll
                for (int r = 0; r < 4; ++r) {
                    int row = rowb + mi * 16 + quad * 4 + r;
                    float val = acc[mi][ni][r] + bi;
                    if (col < 64) offb[(size_t)row * 64 + col] = f2bf(val);
                    else          awb[(size_t)row * 32 + (col - 64)] = f2bf(val);
                }
            }
        }
    }
}

// ---------------------------------------------------------------------------
// deformable sampling: one wave per (b,j); lane = (head, 8 channels)
// ---------------------------------------------------------------------------
__global__ __launch_bounds__(256) void sample_kernel(
    const float* __restrict__ ref, const u16* __restrict__ off,
    const u16* __restrict__ aw, const u16* __restrict__ v,
    u16* __restrict__ out)
{
    int bj = blockIdx.x * 4 + (threadIdx.x >> 6);   // b*N + j
    int lane = threadIdx.x & 63;
    int h  = lane >> 3;
    int d8 = (lane & 7) * 8;
    int b  = bj >> 14;

    float rx = ref[(size_t)bj * 2 + 0];
    float ry = ref[(size_t)bj * 2 + 1];
    uint4 offv = *(const uint4*)(off + (size_t)bj * 64 + h * 8);
    uint2 awv  = *(const uint2*)(aw + (size_t)bj * 32 + h * 4);

    float l0 = bf2f((u16)(awv.x & 0xffff)), l1 = bf2f((u16)(awv.x >> 16));
    float l2 = bf2f((u16)(awv.y & 0xffff)), l3 = bf2f((u16)(awv.y >> 16));
    float mx = fmaxf(fmaxf(l0, l1), fmaxf(l2, l3));
    float e[4];
    e[0] = expf(l0 - mx); e[1] = expf(l1 - mx);
    e[2] = expf(l2 - mx); e[3] = expf(l3 - mx);
    float inv_es = 1.0f / (e[0] + e[1] + e[2] + e[3]);

    const u16* vb = v + (size_t)b * NDIM * CDIM + h * HEAD_DIM + d8;
    float acc[8] = {0.f, 0.f, 0.f, 0.f, 0.f, 0.f, 0.f, 0.f};
    unsigned ow[4] = {offv.x, offv.y, offv.z, offv.w};

#pragma unroll
    for (int p = 0; p < NPTS; ++p) {
        float ox = bf2f((u16)(ow[p] & 0xffff));
        float oy = bf2f((u16)(ow[p] >> 16));
        float X = rx * (float)WDIM + ox - 0.5f;
        float Y = ry * (float)HDIM + oy - 0.5f;
        float x0f = floorf(X), y0f = floorf(Y);
        float wx = X - x0f, wy = Y - y0f;
        int x0 = (int)x0f, y0 = (int)y0f;
        float ep = e[p];
#pragma unroll
        for (int cy = 0; cy < 2; ++cy) {
            int yy = y0 + cy;
            float wyc = cy ? wy : (1.0f - wy);
            int yin = (yy >= 0) & (yy < HDIM);
            int yc = min(max(yy, 0), HDIM - 1);
#pragma unroll
            for (int cx = 0; cx < 2; ++cx) {
                int xx = x0 + cx;
                float wxc = cx ? wx : (1.0f - wx);
                int xin = (xx >= 0) & (xx < WDIM);
                int xc = min(max(xx, 0), WDIM - 1);
                float wgt = ep * wyc * wxc * (float)(yin & xin);
                uint4 vv = *(const uint4*)(vb + (size_t)(yc * WDIM + xc) * CDIM);
                acc[0] += wgt * bf2f((u16)(vv.x & 0xffff));
                acc[1] += wgt * bf2f((u16)(vv.x >> 16));
                acc[2] += wgt * bf2f((u16)(vv.y & 0xffff));
                acc[3] += wgt * bf2f((u16)(vv.y >> 16));
                acc[4] += wgt * bf2f((u16)(vv.z & 0xffff));
                acc[5] += wgt * bf2f((u16)(vv.z >> 16));
                acc[6] += wgt * bf2f((u16)(vv.w & 0xffff));
                acc[7] += wgt * bf2f((u16)(vv.w >> 16));
            }
        }
    }
    uint4 r;
    r.x = (unsigned)f2bf(acc[0] * inv_es) | ((unsigned)f2bf(acc[1] * inv_es) << 16);
    r.y = (unsigned)f2bf(acc[2] * inv_es) | ((unsigned)f2bf(acc[3] * inv_es) << 16);
    r.z = (unsigned)f2bf(acc[4] * inv_es) | ((unsigned)f2bf(acc[5] * inv_es) << 16);
    r.w = (unsigned)f2bf(acc[6] * inv_es) | ((unsigned)f2bf(acc[7] * inv_es) << 16);
    *(uint4*)(out + (size_t)bj * CDIM + h * HEAD_DIM + d8) = r;
}

// ---------------------------------------------------------------------------
// launcher
// ---------------------------------------------------------------------------
extern "C" void kernel_launch(void* const* d_in, const int* in_sizes, int n_in,
                              void* d_out, int out_size, void* d_ws, size_t ws_size,
                              hipStream_t stream)
{
    const float* bev   = (const float*)d_in[0];
    const float* lidar = (const float*)d_in[1];
    const float* Wv    = (const float*)d_in[2];
    const float* bv    = (const float*)d_in[3];
    const float* Woff  = (const float*)d_in[4];
    const float* boff  = (const float*)d_in[5];
    const float* Waw   = (const float*)d_in[6];
    const float* baw   = (const float*)d_in[7];
    const float* Wout  = (const float*)d_in[8];
    const float* bout  = (const float*)d_in[9];
    const float* ln1g  = (const float*)d_in[10];
    const float* ln1b  = (const float*)d_in[11];
    const float* W1    = (const float*)d_in[12];
    const float* W2    = (const float*)d_in[13];
    const float* ln2g  = (const float*)d_in[14];
    const float* ln2b  = (const float*)d_in[15];
    const float* peW1  = (const float*)d_in[16];
    const float* peg   = (const float*)d_in[17];
    const float* peb   = (const float*)d_in[18];
    const float* pem   = (const float*)d_in[19];
    const float* pev   = (const float*)d_in[20];
    const float* peW2  = (const float*)d_in[21];

    const size_t NC = (size_t)BN_TOT * CDIM;    // 16,777,216
    const size_t WSZ = 512 * 512;               // one square weight

    char* base = (char*)d_ws;
    u16* q      = (u16*)base;                           // NC bf16 (residual stream)
    u16* actA   = (u16*)(base + NC * 2);                // NC bf16 (v / h / pe-hidden)
    u16* actB   = (u16*)(base + NC * 4);                // NC bf16 (x / sampled)
    u16* wt     = (u16*)(base + NC * 6);                // 25 x 512x512 bf16
    u16* wtv    = wt;                                   // [6]
    u16* wtout  = wt + 6 * WSZ;                         // [6]
    u16* wt1    = wt + 12 * WSZ;                        // [6]
    u16* wt2    = wt + 18 * WSZ;                        // [6]
    u16* wtpe   = wt + 24 * WSZ;                        // [1]
    u16* offawt = wt + 25 * WSZ;                        // 6 x 96x512 bf16
    u16* offb   = offawt + 6 * 96 * 512;                // BN x 64 bf16
    u16* awb    = offb + (size_t)BN_TOT * 64;           // BN x 32 bf16
    float* refb = (float*)(awb + (size_t)BN_TOT * 32);  // BN x 2 fp32
    int* mask   = (int*)(refb + (size_t)BN_TOT * 2);
    int* order  = mask + BN_TOT;
    int* nvalid = order + BN_TOT;

    // d_out doubles as scratch until final scatter:
    u16* qpos_bf = (u16*)d_out;                         // NC bf16 (first half)
    u16* featT   = (u16*)d_out + NC;                    // NC bf16 (second half)

    dim3 blk328(32, 8);
    dim3 gemm_grid(4, 256);        // 128x128 tiles
    dim3 offaw_grid(1, 256);
    int  ln_grid = BN_TOT / 64;    // 512 blocks of 64 rows

    // voxelize
    mask_kernel<<<BN_TOT / 256, 256, 0, stream>>>(lidar, mask);
    order_kernel<<<BDIM, 256, 0, stream>>>(mask, order, nvalid);
    ref_kernel<<<BN_TOT / 256, 256, 0, stream>>>(order, nvalid, refb);
    pack_q_kernel<<<dim3(NDIM / 32, CDIM / 32, BDIM), blk328, 0, stream>>>(lidar, order, nvalid, q);
    bev_conv_kernel<<<dim3(NDIM / 32, CDIM / 32, BDIM), blk328, 0, stream>>>(bev, featT);

    // hoisted weight conversions (all layers at once)
    tconv_b_kernel<<<dim3(16, 16, 6), blk328, 0, stream>>>(Wv,   wtv);
    tconv_b_kernel<<<dim3(16, 16, 6), blk328, 0, stream>>>(Wout, wtout);
    tconv_b_kernel<<<dim3(16, 16, 6), blk328, 0, stream>>>(W1,   wt1);
    tconv_b_kernel<<<dim3(16, 16, 6), blk328, 0, stream>>>(W2,   wt2);
    tconv_b_kernel<<<dim3(16, 16, 1), blk328, 0, stream>>>(peW2, wtpe);
    tconv_offaw_b_kernel<<<dim3(16, 3, 6), blk328, 0, stream>>>(Woff, Waw, offawt);

    // positional embedding: qpos_bf = relu(BN(ref@peW1)) @ peW2
    pe_hidden_kernel<<<BN_TOT, 128, 0, stream>>>(refb, peW1, peg, peb, pem, pev, actA);
    gemm_bf16<<<gemm_grid, 256, 0, stream>>>(actA, wtpe, nullptr, qpos_bf, 0);

    // x0 = q0 + qpos -> actB
    add_bf_kernel<<<(unsigned)(NC / 8 / 256), 256, 0, stream>>>(q, qpos_bf, actB);

    for (int i = 0; i < LNUM; ++i) {
        // off/aw = x @ [Woff|Waw] + bias   (x lives in actB)
        gemm_offaw<<<offaw_grid, 256, 0, stream>>>(actB, offawt + (size_t)i * 96 * 512,
                                                   boff + i * 64, baw + i * 32, offb, awb);
        // v = featT @ Wv + bv -> actA
        gemm_bf16<<<gemm_grid, 256, 0, stream>>>(featT, wtv + (size_t)i * WSZ,
                                                 bv + i * CDIM, actA, 0);
        // sampled -> actB (x dead after offaw)
        sample_kernel<<<BN_TOT / 4, 256, 0, stream>>>(refb, offb, awb, actA, actB);
        // q = LN1(sampled @ Wout + bout + q)
        gemm_ln<<<ln_grid, 512, 0, stream>>>(actB, wtout + (size_t)i * WSZ, bout + i * CDIM,
                                             q, ln1g + i * CDIM, ln1b + i * CDIM,
                                             q, nullptr, nullptr);
        // h = relu(q @ W1) -> actA
        gemm_bf16<<<gemm_grid, 256, 0, stream>>>(q, wt1 + (size_t)i * WSZ, nullptr, actA, 1);
        // q = LN2(h @ W2 + q); x_{i+1} = q + qpos -> actB (skip on last layer)
        gemm_ln<<<ln_grid, 512, 0, stream>>>(actA, wt2 + (size_t)i * WSZ, nullptr,
                                             q, ln2g + i * CDIM, ln2b + i * CDIM,
                                             q, qpos_bf,
                                             (i < LNUM - 1) ? actB : nullptr);
    }

    // scatter back to dense (B, C, H, W) — overwrites all of d_out
    scatter_kernel<<<dim3(NDIM / 32, CDIM / 32, BDIM), blk328, 0, stream>>>(
        q, order, nvalid, (float*)d_out);
}